// Round 12
// baseline (736.466 us; speedup 1.0000x reference)
//
#include <hip/hip_runtime.h>
#include <math.h>

#define NPTS   262144      // B * NPB
#define NPB_   131072
#define K3_    27
#define EPS_   1e-5f
#define WTAP   18432       // bytes per tap in wt: single bf16 plane [co][ci]

typedef __attribute__((ext_vector_type(4)))  short  short4v;
typedef __attribute__((ext_vector_type(8)))  short  short8;
typedef __attribute__((ext_vector_type(8)))  __bf16 bf16x8;
typedef __attribute__((ext_vector_type(16))) float  f32x16;

__device__ __forceinline__ unsigned short f2bf(float f) {   // RNE float -> bf16 bits
    unsigned u = __builtin_bit_cast(unsigned, f);
    u += 0x7FFFu + ((u >> 16) & 1u);
    return (unsigned short)(u >> 16);
}
__device__ __forceinline__ int wswz(int co) {               // row-dependent XOR (bits 4-6)
    return ((co & 7) ^ ((co >> 3) & 3)) << 4;
}

__device__ __forceinline__ void gload_lds16(const void* g, void* l) {
    __builtin_amdgcn_global_load_lds(
        (const __attribute__((address_space(1))) unsigned int*)g,
        (__attribute__((address_space(3))) unsigned int*)l, 16, 0, 0);
}

// ---------------------------------------------------------------------------
// Kernel W-prep: W -> bf16, transposed to [co][ci], XOR-swizzled so linear
// global_load_lds staging lands in swizzled LDS layout.
// element (co,ci): byte off = (co*192 + ci*2) ^ wswz(co)
// ---------------------------------------------------------------------------
__global__ __launch_bounds__(256) void wprep_kernel(
    const float* __restrict__ W, char* __restrict__ wt)
{
    int id = blockIdx.x * 256 + threadIdx.x;
    if (id >= 27 * 96 * 96) return;
    int k = id / 9216, r = id % 9216, co = r / 96, ci = r % 96;
    float w = W[k * 9216 + ci * 96 + co];
    int swz = (co * 192 + ci * 2) ^ wswz(co);
    *(unsigned short*)(wt + (long)k * WTAP + swz) = f2bf(w);
}

// ---------------------------------------------------------------------------
// Kernel X-prep: x[N][96] f32 -> xs[N][96] bf16, plus a zero row at xs[NPTS]
// used for invalid neighbor indices.
// ---------------------------------------------------------------------------
__global__ __launch_bounds__(256) void xprep_kernel(
    const float* __restrict__ x, unsigned short* __restrict__ xs)
{
    const long nquads = (long)NPTS * 24;
    for (long id = (long)blockIdx.x * 256 + threadIdx.x; id < nquads;
         id += (long)gridDim.x * 256) {
        long n = id / 24;
        int  c = (int)(id % 24) * 4;
        float4 v = ((const float4*)x)[id];
        short4v hv = { (short)f2bf(v.x), (short)f2bf(v.y),
                       (short)f2bf(v.z), (short)f2bf(v.w) };
        *(short4v*)(xs + n * 96 + c) = hv;
    }
    if (blockIdx.x == 0 && threadIdx.x < 12) {
        short8 z = {0,0,0,0,0,0,0,0};
        *(short8*)(xs + (long)NPTS * 96 + threadIdx.x * 8) = z;
    }
}

// ---------------------------------------------------------------------------
// conv helpers
// ---------------------------------------------------------------------------
__device__ __forceinline__ void load_a(
    short8 dst[2], const unsigned short* b0, const unsigned short* b1, int soff)
{
    dst[0] = *(const short8*)(b0 + soff);
    dst[1] = *(const short8*)(b1 + soff);
}

__device__ __forceinline__ void mfma_step(
    f32x16 acc[2][3], const short8 ab[2],
    const char* wbase, int cioff2, const int* cobase, int xorv)
{
    bf16x8 a0 = __builtin_bit_cast(bf16x8, ab[0]);
    bf16x8 a1 = __builtin_bit_cast(bf16x8, ab[1]);
    #pragma unroll
    for (int n = 0; n < 3; ++n) {
        int a = (cobase[n] + cioff2) ^ xorv;
        bf16x8 bh = __builtin_bit_cast(bf16x8, *(const short8*)(wbase + a));
        acc[0][n] = __builtin_amdgcn_mfma_f32_32x32x16_bf16(a0, bh, acc[0][n], 0, 0, 0);
        acc[1][n] = __builtin_amdgcn_mfma_f32_32x32x16_bf16(a1, bh, acc[1][n], 0, 0, 0);
    }
}

__device__ __forceinline__ void stage_w(const char* g, char* lp, int tid)
{
    #pragma unroll
    for (int i = 0; i < 4; ++i)
        gload_lds16(g + tid * 16 + i * 4096, lp + tid * 16 + i * 4096);
    if (tid < 128)
        gload_lds16(g + 16384 + tid * 16, lp + 16384 + tid * 16);
}

// ---------------------------------------------------------------------------
// Kernel conv (v7): pure bf16, 256 thr / 4 waves, 256 rows per block.
// LDS = W double-buffer only (36 KB); stats scratch aliased into wlds after
// the K-loop -> 4 blocks/CU (launch_bounds(256,4)), 16 waves/CU for gather
// latency hiding. 6-slot A ring + raw s_barrier + counted vmcnt(10).
// ---------------------------------------------------------------------------
__global__ __launch_bounds__(256, 4) void conv_mfma(
    const unsigned short* __restrict__ xs, const int* __restrict__ nbr,
    const char* __restrict__ wt, float* __restrict__ hout,
    float* __restrict__ partials)
{
    __shared__ __align__(16) char wlds[2][WTAP];   // 36 KB total

    const int tid = threadIdx.x;
    const int wv  = tid >> 6;
    const int l   = tid & 63;
    const int l31 = l & 31;
    const int lh  = l >> 5;
    const int blockM = blockIdx.x * 256;
    const int row0 = blockM + wv * 64 + l31;
    const int row1 = row0 + 32;

    f32x16 acc[2][3] = {};
    const int xorv = wswz(l31);
    int cobase[3];
    #pragma unroll
    for (int n = 0; n < 3; ++n) cobase[n] = (n * 32 + l31) * 192;

    // prologue: stage tap-0 W; tap-0/1 indices; prime slots 0..4
    stage_w(wt, wlds[0], tid);
    int idx0 = nbr[row0 * 27];
    int idx1 = nbr[row1 * 27];
    int jdx0 = nbr[row0 * 27 + 1];
    int jdx1 = nbr[row1 * 27 + 1];
    const unsigned short* b0 = xs + (long)(idx0 >= 0 ? idx0 : NPTS) * 96;
    const unsigned short* b1 = xs + (long)(idx1 >= 0 ? idx1 : NPTS) * 96;

    short8 abuf[6][2];                       // 6-slot ring, statically indexed
    load_a(abuf[0], b0, b1,  0 + lh * 8);
    load_a(abuf[1], b0, b1, 16 + lh * 8);
    load_a(abuf[2], b0, b1, 32 + lh * 8);
    load_a(abuf[3], b0, b1, 48 + lh * 8);
    load_a(abuf[4], b0, b1, 64 + lh * 8);

    #pragma unroll 1
    for (int k = 0; k < 27; ++k) {
        // boundary: vmcnt(10) retires all but the 10 newest VMEM ops (the 5
        // prefetched A sets) -> this wave's W LDS-writes complete before the
        // raw barrier; A pipeline stays live across it.
        __builtin_amdgcn_sched_barrier(0);
        asm volatile("s_waitcnt vmcnt(10)" ::: "memory");
        __builtin_amdgcn_sched_barrier(0);
        __builtin_amdgcn_s_barrier();
        __builtin_amdgcn_sched_barrier(0);

        const char* wbase = wlds[k & 1];
        if (k < 26)                           // stage W(k+1)
            stage_w(wt + (long)(k + 1) * WTAP, wlds[(k + 1) & 1], tid);
        const int kn = (k + 2 <= 26) ? (k + 2) : 26;
        int t0 = nbr[row0 * 27 + kn];         // 2-tap-ahead index prefetch
        int t1 = nbr[row1 * 27 + kn];
        const unsigned short* nb0 = xs + (long)(jdx0 >= 0 ? jdx0 : NPTS) * 96;
        const unsigned short* nb1 = xs + (long)(jdx1 >= 0 ? jdx1 : NPTS) * 96;

        // step s consumes slot s; issues the set for global step s+5
        load_a(abuf[5], b0, b1, 80 + lh * 8);
        mfma_step(acc, abuf[0], wbase,   0 + lh * 16, cobase, xorv);
        load_a(abuf[0], nb0, nb1,  0 + lh * 8);
        mfma_step(acc, abuf[1], wbase,  32 + lh * 16, cobase, xorv);
        load_a(abuf[1], nb0, nb1, 16 + lh * 8);
        mfma_step(acc, abuf[2], wbase,  64 + lh * 16, cobase, xorv);
        load_a(abuf[2], nb0, nb1, 32 + lh * 8);
        mfma_step(acc, abuf[3], wbase,  96 + lh * 16, cobase, xorv);
        load_a(abuf[3], nb0, nb1, 48 + lh * 8);
        mfma_step(acc, abuf[4], wbase, 128 + lh * 16, cobase, xorv);
        load_a(abuf[4], nb0, nb1, 64 + lh * 8);
        mfma_step(acc, abuf[5], wbase, 160 + lh * 16, cobase, xorv);

        b0 = nb0; b1 = nb1;
        jdx0 = t0; jdx1 = t1;
    }

    // ---- write h (C/D layout: col = lane&31, row = (r&3) + 8*(r>>2) + 4*lh)
    #pragma unroll
    for (int ms = 0; ms < 2; ++ms)
        #pragma unroll
        for (int n = 0; n < 3; ++n)
            #pragma unroll
            for (int r = 0; r < 16; ++r) {
                int rw = (r & 3) + 8 * (r >> 2) + 4 * lh;
                hout[(long)(blockM + wv * 64 + ms * 32 + rw) * 96 + n * 32 + l31] = acc[ms][n][r];
            }

    // ---- fused per-block channel stats (sum / sumsq / max)
    float sv[3], qv[3], mv[3];
    #pragma unroll
    for (int n = 0; n < 3; ++n) { sv[n] = 0.f; qv[n] = 0.f; mv[n] = -INFINITY; }
    #pragma unroll
    for (int ms = 0; ms < 2; ++ms)
        #pragma unroll
        for (int n = 0; n < 3; ++n)
            #pragma unroll
            for (int r = 0; r < 16; ++r) {
                float v = acc[ms][n][r];
                sv[n] += v;
                qv[n] = fmaf(v, v, qv[n]);
                mv[n] = fmaxf(mv[n], v);
            }
    #pragma unroll
    for (int n = 0; n < 3; ++n) {
        sv[n] += __shfl_xor(sv[n], 32);
        qv[n] += __shfl_xor(qv[n], 32);
        mv[n] = fmaxf(mv[n], __shfl_xor(mv[n], 32));
    }
    // stats scratch aliased into wlds (W dead after K-loop); barrier first so
    // every wave has finished its LDS reads before we overwrite.
    float (*red)[3][32][3] = (float (*)[3][32][3])(&wlds[0][0]);
    __syncthreads();
    if (lh == 0) {
        #pragma unroll
        for (int n = 0; n < 3; ++n) {
            red[wv][n][l31][0] = sv[n];
            red[wv][n][l31][1] = qv[n];
            red[wv][n][l31][2] = mv[n];
        }
    }
    __syncthreads();
    if (tid < 96) {
        int n = tid >> 5, c = tid & 31;
        float S = 0.f, Q = 0.f, M = -INFINITY;
        #pragma unroll
        for (int w = 0; w < 4; ++w) {
            S += red[w][n][c][0];
            Q += red[w][n][c][1];
            M = fmaxf(M, red[w][n][c][2]);
        }
        float* op = partials + (long)blockIdx.x * 288;
        op[tid] = S; op[96 + tid] = Q; op[192 + tid] = M;
    }
}

// ---------------------------------------------------------------------------
// Fallback conv (fp32 source, in-kernel bf16 convert, single-term) used when
// ws_size can't hold xs. Same numerics as main path.
// ---------------------------------------------------------------------------
__global__ __launch_bounds__(256, 2) void conv_mfma_cvt(
    const float* __restrict__ x, const int* __restrict__ nbr,
    const char* __restrict__ wt, float* __restrict__ hout,
    float* __restrict__ partials)
{
    __shared__ __align__(16) char wlds[WTAP];
    __shared__ float red[4][3][32][3];

    const int tid = threadIdx.x;
    const int wv  = tid >> 6;
    const int l   = tid & 63;
    const int l31 = l & 31;
    const int lh  = l >> 5;
    const int blockM = blockIdx.x * 256;
    const int row0 = blockM + wv * 64 + l31;
    const int row1 = row0 + 32;

    f32x16 acc[2][3] = {};
    const int xorv = wswz(l31);
    int cobase[3];
    #pragma unroll
    for (int n = 0; n < 3; ++n) cobase[n] = (n * 32 + l31) * 192;

    int idx0 = nbr[row0 * 27];
    int idx1 = nbr[row1 * 27];

    #pragma unroll 1
    for (int k = 0; k < 27; ++k) {
        __syncthreads();
        stage_w(wt + (long)k * WTAP, wlds, tid);
        __syncthreads();

        #pragma unroll
        for (int s = 0; s < 6; ++s) {
            float4 q0 = make_float4(0,0,0,0), q1 = q0, p0 = q0, p1 = q0;
            if (idx0 >= 0) {
                q0 = *(const float4*)(x + (long)idx0 * 96 + s * 16 + lh * 8);
                q1 = *(const float4*)(x + (long)idx0 * 96 + s * 16 + lh * 8 + 4);
            }
            if (idx1 >= 0) {
                p0 = *(const float4*)(x + (long)idx1 * 96 + s * 16 + lh * 8);
                p1 = *(const float4*)(x + (long)idx1 * 96 + s * 16 + lh * 8 + 4);
            }
            short8 ab[2];
            float a0[8] = {q0.x,q0.y,q0.z,q0.w,q1.x,q1.y,q1.z,q1.w};
            float a1[8] = {p0.x,p0.y,p0.z,p0.w,p1.x,p1.y,p1.z,p1.w};
            #pragma unroll
            for (int j = 0; j < 8; ++j) {
                ab[0][j] = (short)f2bf(a0[j]);
                ab[1][j] = (short)f2bf(a1[j]);
            }
            mfma_step(acc, ab, wlds, s * 32 + lh * 16, cobase, xorv);
        }
        if (k < 26) {
            idx0 = nbr[row0 * 27 + k + 1];
            idx1 = nbr[row1 * 27 + k + 1];
        }
    }

    #pragma unroll
    for (int ms = 0; ms < 2; ++ms)
        #pragma unroll
        for (int n = 0; n < 3; ++n)
            #pragma unroll
            for (int r = 0; r < 16; ++r) {
                int rw = (r & 3) + 8 * (r >> 2) + 4 * lh;
                hout[(long)(blockM + wv * 64 + ms * 32 + rw) * 96 + n * 32 + l31] = acc[ms][n][r];
            }

    float sv[3], qv[3], mv[3];
    #pragma unroll
    for (int n = 0; n < 3; ++n) { sv[n] = 0.f; qv[n] = 0.f; mv[n] = -INFINITY; }
    #pragma unroll
    for (int ms = 0; ms < 2; ++ms)
        #pragma unroll
        for (int n = 0; n < 3; ++n)
            #pragma unroll
            for (int r = 0; r < 16; ++r) {
                float v = acc[ms][n][r];
                sv[n] += v; qv[n] = fmaf(v, v, qv[n]); mv[n] = fmaxf(mv[n], v);
            }
    #pragma unroll
    for (int n = 0; n < 3; ++n) {
        sv[n] += __shfl_xor(sv[n], 32);
        qv[n] += __shfl_xor(qv[n], 32);
        mv[n] = fmaxf(mv[n], __shfl_xor(mv[n], 32));
    }
    if (lh == 0) {
        #pragma unroll
        for (int n = 0; n < 3; ++n) {
            red[wv][n][l31][0] = sv[n];
            red[wv][n][l31][1] = qv[n];
            red[wv][n][l31][2] = mv[n];
        }
    }
    __syncthreads();
    if (tid < 96) {
        int n = tid >> 5, c = tid & 31;
        float S = 0.f, Q = 0.f, M = -INFINITY;
        #pragma unroll
        for (int w = 0; w < 4; ++w) {
            S += red[w][n][c][0];
            Q += red[w][n][c][1];
            M = fmaxf(M, red[w][n][c][2]);
        }
        float* op = partials + (long)blockIdx.x * 288;
        op[tid] = S; op[96 + tid] = Q; op[192 + tid] = M;
    }
}

// ---------------------------------------------------------------------------
// Kernel attn: reduce partials (4-way chunked, 384 thr) -> scene stats;
// attention MLP + softmax; analytic BN stats. Single block.
// ---------------------------------------------------------------------------
__global__ __launch_bounds__(384) void attn_kernel(
    const float* __restrict__ partials, int nper,
    const float* __restrict__ w1, const float* __restrict__ bias1,
    const float* __restrict__ w2, const float* __restrict__ bias2,
    float* __restrict__ smal)
{
    __shared__ float rS[2][4][96], rQ[2][4][96], rM[2][4][96];
    __shared__ float Sb[2][96], Qb[2][96];
    __shared__ float vecs[4][96];
    __shared__ float hid[4][48];
    __shared__ float logit[2][96];
    __shared__ float attn[2][96];
    __shared__ float red2[2][2];
    const int t = threadIdx.x;
    const int c = t % 96, j = t / 96;
    const int chunk = nper / 4;

    for (int b = 0; b < 2; ++b) {
        float s = 0.f, q = 0.f, m = -INFINITY;
        const float* pp = partials + (long)b * nper * 288 + (long)j * chunk * 288;
        for (int i = 0; i < chunk; ++i) {
            s += pp[i * 288 + c];
            q += pp[i * 288 + 96 + c];
            m = fmaxf(m, pp[i * 288 + 192 + c]);
        }
        rS[b][j][c] = s; rQ[b][j][c] = q; rM[b][j][c] = m;
    }
    __syncthreads();

    if (t < 96) {
        for (int b = 0; b < 2; ++b) {
            float s = 0.f, q = 0.f, m = -INFINITY;
            #pragma unroll
            for (int jj = 0; jj < 4; ++jj) {
                s += rS[b][jj][t];
                q += rQ[b][jj][t];
                m = fmaxf(m, rM[b][jj][t]);
            }
            Sb[b][t] = s;
            Qb[b][t] = q;
            vecs[2 * b][t]     = s * (1.0f / (float)NPB_);
            vecs[2 * b + 1][t] = m;
        }
    }
    __syncthreads();

    for (int v = 0; v < 4; ++v) {
        if (t < 48) {
            float a = bias1[t];
            for (int cc = 0; cc < 96; ++cc) a = fmaf(vecs[v][cc], w1[cc * 48 + t], a);
            hid[v][t] = fmaxf(a, 0.f);
        }
    }
    __syncthreads();

    if (t < 96) {
        for (int b = 0; b < 2; ++b) {
            float om = bias2[t], ox = bias2[t];
            for (int jj = 0; jj < 48; ++jj) {
                om = fmaf(hid[2 * b][jj],     w2[jj * 96 + t], om);
                ox = fmaf(hid[2 * b + 1][jj], w2[jj * 96 + t], ox);
            }
            logit[b][t] = fmaxf(om, 0.f) + fmaxf(ox, 0.f);
        }
    }
    __syncthreads();

    if (t < 2) {
        float mx = -INFINITY;
        for (int cc = 0; cc < 96; ++cc) mx = fmaxf(mx, logit[t][cc]);
        float s = 0.f;
        for (int cc = 0; cc < 96; ++cc) s += __expf(logit[t][cc] - mx);
        red2[t][0] = mx;
        red2[t][1] = s;
    }
    __syncthreads();
    if (t < 96) {
        for (int b = 0; b < 2; ++b)
            attn[b][t] = __expf(logit[b][t] - red2[b][0]) / red2[b][1];
    }
    __syncthreads();

    if (t < 96) {
        float a0 = attn[0][t], a1 = attn[1][t];
        const float invN = 1.0f / (float)NPTS;
        float mu = (a0 * Sb[0][t] + a1 * Sb[1][t]) * invN;
        float e2 = (a0 * a0 * Qb[0][t] + a1 * a1 * Qb[1][t]) * invN;
        float var = e2 - mu * mu;
        smal[t]       = a0;
        smal[96 + t]  = a1;
        smal[192 + t] = mu;
        smal[288 + t] = rsqrtf(var + EPS_);
    }
}

// ---------------------------------------------------------------------------
// Kernel finalize (in place on d_out which holds h):
// out = relu( relu(gamma*(h*attn - mu)*invstd + beta) + x )
// ---------------------------------------------------------------------------
__global__ __launch_bounds__(256) void final_kernel(
    const float* __restrict__ x, const float* __restrict__ smal,
    const float* __restrict__ gamma, const float* __restrict__ beta,
    float* __restrict__ out)
{
    const int nq = NPTS * 24;
    const int sceneq = NPB_ * 24;
    for (int i = blockIdx.x * 256 + threadIdx.x; i < nq; i += gridDim.x * 256) {
        const int b = (i >= sceneq) ? 1 : 0;
        const int q = i % 24;
        float4 h4 = ((const float4*)out)[i];
        float4 x4 = ((const float4*)x)[i];
        float4 a4  = ((const float4*)(smal + b * 96))[q];
        float4 mu4 = ((const float4*)(smal + 192))[q];
        float4 is4 = ((const float4*)(smal + 288))[q];
        float4 g4  = ((const float4*)gamma)[q];
        float4 be4 = ((const float4*)beta)[q];
        float4 r;
        r.x = fmaxf(fmaxf(fmaf((h4.x * a4.x - mu4.x) * is4.x, g4.x, be4.x), 0.f) + x4.x, 0.f);
        r.y = fmaxf(fmaxf(fmaf((h4.y * a4.y - mu4.y) * is4.y, g4.y, be4.y), 0.f) + x4.y, 0.f);
        r.z = fmaxf(fmaxf(fmaf((h4.z * a4.z - mu4.z) * is4.z, g4.z, be4.z), 0.f) + x4.z, 0.f);
        r.w = fmaxf(fmaxf(fmaf((h4.w * a4.w - mu4.w) * is4.w, g4.w, be4.w), 0.f) + x4.w, 0.f);
        ((float4*)out)[i] = r;
    }
}

// ---------------------------------------------------------------------------
extern "C" void kernel_launch(void* const* d_in, const int* in_sizes, int n_in,
                              void* d_out, int out_size, void* d_ws, size_t ws_size,
                              hipStream_t stream)
{
    const float* x     = (const float*)d_in[0];
    const int*   nbr   = (const int*)  d_in[1];
    const float* W     = (const float*)d_in[2];
    const float* w1    = (const float*)d_in[3];
    const float* b1    = (const float*)d_in[4];
    const float* w2    = (const float*)d_in[5];
    const float* b2    = (const float*)d_in[6];
    const float* gamma = (const float*)d_in[7];
    const float* beta  = (const float*)d_in[8];
    float* out = (float*)d_out;

    const size_t WT_BYTES   = 27UL * WTAP;                   // 497664
    const size_t XS_BYTES   = (size_t)(NPTS + 1) * 96 * 2;   // ~50.3 MB (+zero row)
    const size_t PART_BYTES = 1024UL * 288 * 4;              // 1179648

    char* wt = (char*)d_ws;
    wprep_kernel<<<972, 256, 0, stream>>>(W, wt);

    if (ws_size >= WT_BYTES + XS_BYTES + PART_BYTES + 2048) {
        unsigned short* xs = (unsigned short*)(wt + WT_BYTES);
        float* partials = (float*)(wt + WT_BYTES + XS_BYTES);
        float* smal     = partials + 1024 * 288;
        xprep_kernel<<<2048, 256, 0, stream>>>(x, xs);
        conv_mfma   <<<1024, 256, 0, stream>>>(xs, nbr, wt, out, partials);
        attn_kernel <<<1, 384, 0, stream>>>(partials, 512, w1, b1, w2, b2, smal);
        final_kernel<<<1024, 256, 0, stream>>>(x, smal, gamma, beta, out);
    } else {
        float* partials = (float*)(wt + WT_BYTES);
        float* smal     = partials + 1024 * 288;
        conv_mfma_cvt<<<1024, 256, 0, stream>>>(x, nbr, wt, out, partials);
        attn_kernel <<<1, 384, 0, stream>>>(partials, 512, w1, b1, w2, b2, smal);
        final_kernel<<<1024, 256, 0, stream>>>(x, smal, gamma, beta, out);
    }
}

// Round 13
// 305.451 us; speedup vs baseline: 2.4111x; 2.4111x over previous
//
#include <hip/hip_runtime.h>
#include <math.h>

#define NPTS   262144      // B * NPB
#define NPB_   131072
#define K3_    27
#define EPS_   1e-5f
#define WTAP   18432       // bytes per tap in wt: single bf16 plane [co][ci]

typedef __attribute__((ext_vector_type(4)))  short  short4v;
typedef __attribute__((ext_vector_type(8)))  short  short8;
typedef __attribute__((ext_vector_type(8)))  __bf16 bf16x8;
typedef __attribute__((ext_vector_type(16))) float  f32x16;

__device__ __forceinline__ unsigned short f2bf(float f) {   // RNE float -> bf16 bits
    unsigned u = __builtin_bit_cast(unsigned, f);
    u += 0x7FFFu + ((u >> 16) & 1u);
    return (unsigned short)(u >> 16);
}
__device__ __forceinline__ int wswz(int co) {               // row-dependent XOR (bits 4-6)
    return ((co & 7) ^ ((co >> 3) & 3)) << 4;
}

__device__ __forceinline__ void gload_lds16(const void* g, void* l) {
    __builtin_amdgcn_global_load_lds(
        (const __attribute__((address_space(1))) unsigned int*)g,
        (__attribute__((address_space(3))) unsigned int*)l, 16, 0, 0);
}

// ---------------------------------------------------------------------------
// Kernel W-prep: W -> bf16, transposed to [co][ci], XOR-swizzled so linear
// global_load_lds staging lands in swizzled LDS layout.
// element (co,ci): byte off = (co*192 + ci*2) ^ wswz(co)
// ---------------------------------------------------------------------------
__global__ __launch_bounds__(256) void wprep_kernel(
    const float* __restrict__ W, char* __restrict__ wt)
{
    int id = blockIdx.x * 256 + threadIdx.x;
    if (id >= 27 * 96 * 96) return;
    int k = id / 9216, r = id % 9216, co = r / 96, ci = r % 96;
    float w = W[k * 9216 + ci * 96 + co];
    int swz = (co * 192 + ci * 2) ^ wswz(co);
    *(unsigned short*)(wt + (long)k * WTAP + swz) = f2bf(w);
}

// ---------------------------------------------------------------------------
// Kernel X-prep: x[N][96] f32 -> xs[N][96] bf16, plus a zero row at xs[NPTS]
// used for invalid neighbor indices.
// ---------------------------------------------------------------------------
__global__ __launch_bounds__(256) void xprep_kernel(
    const float* __restrict__ x, unsigned short* __restrict__ xs)
{
    const long nquads = (long)NPTS * 24;
    for (long id = (long)blockIdx.x * 256 + threadIdx.x; id < nquads;
         id += (long)gridDim.x * 256) {
        long n = id / 24;
        int  c = (int)(id % 24) * 4;
        float4 v = ((const float4*)x)[id];
        short4v hv = { (short)f2bf(v.x), (short)f2bf(v.y),
                       (short)f2bf(v.z), (short)f2bf(v.w) };
        *(short4v*)(xs + n * 96 + c) = hv;
    }
    if (blockIdx.x == 0 && threadIdx.x < 12) {
        short8 z = {0,0,0,0,0,0,0,0};
        *(short8*)(xs + (long)NPTS * 96 + threadIdx.x * 8) = z;
    }
}

// ---------------------------------------------------------------------------
// conv helpers
// ---------------------------------------------------------------------------
__device__ __forceinline__ void mfma_step1(
    f32x16 acc[3], short8 a,
    const char* wbase, int cioff2, const int* cobase, int xorv)
{
    bf16x8 av = __builtin_bit_cast(bf16x8, a);
    #pragma unroll
    for (int n = 0; n < 3; ++n) {
        int ad = (cobase[n] + cioff2) ^ xorv;
        bf16x8 bh = __builtin_bit_cast(bf16x8, *(const short8*)(wbase + ad));
        acc[n] = __builtin_amdgcn_mfma_f32_32x32x16_bf16(av, bh, acc[n], 0, 0, 0);
    }
}

__device__ __forceinline__ void stage_w(const char* g, char* lp, int tid)
{
    #pragma unroll
    for (int i = 0; i < 4; ++i)
        gload_lds16(g + tid * 16 + i * 4096, lp + tid * 16 + i * 4096);
    if (tid < 128)
        gload_lds16(g + 16384 + tid * 16, lp + 16384 + tid * 16);
}

// ---------------------------------------------------------------------------
// Kernel conv (v8): pure bf16, 1 row per lane (32 rows/wave), 256 thr/4 waves
// = 128 rows per block, grid 2048. Small register state (acc 48 + ring 24)
// -> clean 4 blocks/CU x 4 waves = 16 waves/CU for gather TLP.
// W double-buffered in LDS (36 KB); stats scratch aliased into wlds.
// 6-slot A ring + raw s_barrier + counted vmcnt(5).
// ---------------------------------------------------------------------------
__global__ __launch_bounds__(256, 4) void conv_mfma(
    const unsigned short* __restrict__ xs, const int* __restrict__ nbr,
    const char* __restrict__ wt, float* __restrict__ hout,
    float* __restrict__ partials)
{
    __shared__ __align__(16) char wlds[2][WTAP];   // 36 KB total

    const int tid = threadIdx.x;
    const int wv  = tid >> 6;
    const int l   = tid & 63;
    const int l31 = l & 31;
    const int lh  = l >> 5;
    const int blockM = blockIdx.x * 128;
    const int row0 = blockM + wv * 32 + l31;

    f32x16 acc[3] = {};
    const int xorv = wswz(l31);
    int cobase[3];
    #pragma unroll
    for (int n = 0; n < 3; ++n) cobase[n] = (n * 32 + l31) * 192;

    // prologue: stage tap-0 W; tap-0/1 indices; prime slots 0..4
    stage_w(wt, wlds[0], tid);
    int idx0 = nbr[row0 * 27];
    int jdx0 = nbr[row0 * 27 + 1];
    const unsigned short* b0 = xs + (long)(idx0 >= 0 ? idx0 : NPTS) * 96;

    short8 abuf[6];                          // 6-slot ring, statically indexed
    abuf[0] = *(const short8*)(b0 +  0 + lh * 8);
    abuf[1] = *(const short8*)(b0 + 16 + lh * 8);
    abuf[2] = *(const short8*)(b0 + 32 + lh * 8);
    abuf[3] = *(const short8*)(b0 + 48 + lh * 8);
    abuf[4] = *(const short8*)(b0 + 64 + lh * 8);

    #pragma unroll 1
    for (int k = 0; k < 27; ++k) {
        // boundary: vmcnt(5) retires all but the 5 newest VMEM ops (the
        // prefetched A sets for the next tap) -> this wave's W LDS-writes
        // complete before the raw barrier; A pipeline stays live across it.
        __builtin_amdgcn_sched_barrier(0);
        asm volatile("s_waitcnt vmcnt(5)" ::: "memory");
        __builtin_amdgcn_sched_barrier(0);
        __builtin_amdgcn_s_barrier();
        __builtin_amdgcn_sched_barrier(0);

        const char* wbase = wlds[k & 1];
        if (k < 26)                           // stage W(k+1)
            stage_w(wt + (long)(k + 1) * WTAP, wlds[(k + 1) & 1], tid);
        const int kn = (k + 2 <= 26) ? (k + 2) : 26;
        int t0 = nbr[row0 * 27 + kn];         // 2-tap-ahead index prefetch
        const unsigned short* nb0 = xs + (long)(jdx0 >= 0 ? jdx0 : NPTS) * 96;

        // step s consumes slot s; refills go to next tap's steps 0..4
        abuf[5] = *(const short8*)(b0 + 80 + lh * 8);
        mfma_step1(acc, abuf[0], wbase,   0 + lh * 16, cobase, xorv);
        abuf[0] = *(const short8*)(nb0 +  0 + lh * 8);
        mfma_step1(acc, abuf[1], wbase,  32 + lh * 16, cobase, xorv);
        abuf[1] = *(const short8*)(nb0 + 16 + lh * 8);
        mfma_step1(acc, abuf[2], wbase,  64 + lh * 16, cobase, xorv);
        abuf[2] = *(const short8*)(nb0 + 32 + lh * 8);
        mfma_step1(acc, abuf[3], wbase,  96 + lh * 16, cobase, xorv);
        abuf[3] = *(const short8*)(nb0 + 48 + lh * 8);
        mfma_step1(acc, abuf[4], wbase, 128 + lh * 16, cobase, xorv);
        abuf[4] = *(const short8*)(nb0 + 64 + lh * 8);
        mfma_step1(acc, abuf[5], wbase, 160 + lh * 16, cobase, xorv);

        b0 = nb0;
        jdx0 = t0;
    }

    // ---- write h (C/D layout: col = lane&31, row = (r&3) + 8*(r>>2) + 4*lh)
    #pragma unroll
    for (int n = 0; n < 3; ++n)
        #pragma unroll
        for (int r = 0; r < 16; ++r) {
            int rw = (r & 3) + 8 * (r >> 2) + 4 * lh;
            hout[(long)(blockM + wv * 32 + rw) * 96 + n * 32 + l31] = acc[n][r];
        }

    // ---- fused per-block channel stats (sum / sumsq / max)
    float sv[3], qv[3], mv[3];
    #pragma unroll
    for (int n = 0; n < 3; ++n) { sv[n] = 0.f; qv[n] = 0.f; mv[n] = -INFINITY; }
    #pragma unroll
    for (int n = 0; n < 3; ++n)
        #pragma unroll
        for (int r = 0; r < 16; ++r) {
            float v = acc[n][r];
            sv[n] += v;
            qv[n] = fmaf(v, v, qv[n]);
            mv[n] = fmaxf(mv[n], v);
        }
    #pragma unroll
    for (int n = 0; n < 3; ++n) {
        sv[n] += __shfl_xor(sv[n], 32);
        qv[n] += __shfl_xor(qv[n], 32);
        mv[n] = fmaxf(mv[n], __shfl_xor(mv[n], 32));
    }
    // stats scratch aliased into wlds (W dead after K-loop)
    float (*red)[3][32][3] = (float (*)[3][32][3])(&wlds[0][0]);
    __syncthreads();
    if (lh == 0) {
        #pragma unroll
        for (int n = 0; n < 3; ++n) {
            red[wv][n][l31][0] = sv[n];
            red[wv][n][l31][1] = qv[n];
            red[wv][n][l31][2] = mv[n];
        }
    }
    __syncthreads();
    if (tid < 96) {
        int n = tid >> 5, c = tid & 31;
        float S = 0.f, Q = 0.f, M = -INFINITY;
        #pragma unroll
        for (int w = 0; w < 4; ++w) {
            S += red[w][n][c][0];
            Q += red[w][n][c][1];
            M = fmaxf(M, red[w][n][c][2]);
        }
        float* op = partials + (long)blockIdx.x * 288;
        op[tid] = S; op[96 + tid] = Q; op[192 + tid] = M;
    }
}

// ---------------------------------------------------------------------------
// Fallback conv (fp32 source, in-kernel bf16 convert, single-term) used when
// ws_size can't hold xs. Same numerics as main path. 1024 blocks x 256 thr.
// ---------------------------------------------------------------------------
__global__ __launch_bounds__(256, 2) void conv_mfma_cvt(
    const float* __restrict__ x, const int* __restrict__ nbr,
    const char* __restrict__ wt, float* __restrict__ hout,
    float* __restrict__ partials)
{
    __shared__ __align__(16) char wlds[WTAP];
    __shared__ float red[4][3][32][3];

    const int tid = threadIdx.x;
    const int wv  = tid >> 6;
    const int l   = tid & 63;
    const int l31 = l & 31;
    const int lh  = l >> 5;
    const int blockM = blockIdx.x * 256;
    const int row0 = blockM + wv * 64 + l31;
    const int row1 = row0 + 32;

    f32x16 acc[2][3] = {};
    const int xorv = wswz(l31);
    int cobase[3];
    #pragma unroll
    for (int n = 0; n < 3; ++n) cobase[n] = (n * 32 + l31) * 192;

    int idx0 = nbr[row0 * 27];
    int idx1 = nbr[row1 * 27];

    #pragma unroll 1
    for (int k = 0; k < 27; ++k) {
        __syncthreads();
        stage_w(wt + (long)k * WTAP, wlds, tid);
        __syncthreads();

        #pragma unroll
        for (int s = 0; s < 6; ++s) {
            float4 q0 = make_float4(0,0,0,0), q1 = q0, p0 = q0, p1 = q0;
            if (idx0 >= 0) {
                q0 = *(const float4*)(x + (long)idx0 * 96 + s * 16 + lh * 8);
                q1 = *(const float4*)(x + (long)idx0 * 96 + s * 16 + lh * 8 + 4);
            }
            if (idx1 >= 0) {
                p0 = *(const float4*)(x + (long)idx1 * 96 + s * 16 + lh * 8);
                p1 = *(const float4*)(x + (long)idx1 * 96 + s * 16 + lh * 8 + 4);
            }
            short8 ab0, ab1;
            float a0[8] = {q0.x,q0.y,q0.z,q0.w,q1.x,q1.y,q1.z,q1.w};
            float a1[8] = {p0.x,p0.y,p0.z,p0.w,p1.x,p1.y,p1.z,p1.w};
            #pragma unroll
            for (int j = 0; j < 8; ++j) {
                ab0[j] = (short)f2bf(a0[j]);
                ab1[j] = (short)f2bf(a1[j]);
            }
            bf16x8 av0 = __builtin_bit_cast(bf16x8, ab0);
            bf16x8 av1 = __builtin_bit_cast(bf16x8, ab1);
            const int cioff2 = s * 32 + lh * 16;
            #pragma unroll
            for (int n = 0; n < 3; ++n) {
                int ad = (cobase[n] + cioff2) ^ xorv;
                bf16x8 bh = __builtin_bit_cast(bf16x8, *(const short8*)(wlds + ad));
                acc[0][n] = __builtin_amdgcn_mfma_f32_32x32x16_bf16(av0, bh, acc[0][n], 0, 0, 0);
                acc[1][n] = __builtin_amdgcn_mfma_f32_32x32x16_bf16(av1, bh, acc[1][n], 0, 0, 0);
            }
        }
        if (k < 26) {
            idx0 = nbr[row0 * 27 + k + 1];
            idx1 = nbr[row1 * 27 + k + 1];
        }
    }

    #pragma unroll
    for (int ms = 0; ms < 2; ++ms)
        #pragma unroll
        for (int n = 0; n < 3; ++n)
            #pragma unroll
            for (int r = 0; r < 16; ++r) {
                int rw = (r & 3) + 8 * (r >> 2) + 4 * lh;
                hout[(long)(blockM + wv * 64 + ms * 32 + rw) * 96 + n * 32 + l31] = acc[ms][n][r];
            }

    float sv[3], qv[3], mv[3];
    #pragma unroll
    for (int n = 0; n < 3; ++n) { sv[n] = 0.f; qv[n] = 0.f; mv[n] = -INFINITY; }
    #pragma unroll
    for (int ms = 0; ms < 2; ++ms)
        #pragma unroll
        for (int n = 0; n < 3; ++n)
            #pragma unroll
            for (int r = 0; r < 16; ++r) {
                float v = acc[ms][n][r];
                sv[n] += v; qv[n] = fmaf(v, v, qv[n]); mv[n] = fmaxf(mv[n], v);
            }
    #pragma unroll
    for (int n = 0; n < 3; ++n) {
        sv[n] += __shfl_xor(sv[n], 32);
        qv[n] += __shfl_xor(qv[n], 32);
        mv[n] = fmaxf(mv[n], __shfl_xor(mv[n], 32));
    }
    if (lh == 0) {
        #pragma unroll
        for (int n = 0; n < 3; ++n) {
            red[wv][n][l31][0] = sv[n];
            red[wv][n][l31][1] = qv[n];
            red[wv][n][l31][2] = mv[n];
        }
    }
    __syncthreads();
    if (tid < 96) {
        int n = tid >> 5, c = tid & 31;
        float S = 0.f, Q = 0.f, M = -INFINITY;
        #pragma unroll
        for (int w = 0; w < 4; ++w) {
            S += red[w][n][c][0];
            Q += red[w][n][c][1];
            M = fmaxf(M, red[w][n][c][2]);
        }
        float* op = partials + (long)blockIdx.x * 288;
        op[tid] = S; op[96 + tid] = Q; op[192 + tid] = M;
    }
}

// ---------------------------------------------------------------------------
// Kernel reduce1: collapse 2048 partial rows -> 32 (16 per scene, 64 rows
// each). cols 0..191 sum, 192..287 max.
// ---------------------------------------------------------------------------
__global__ __launch_bounds__(384) void reduce1_kernel(
    const float* __restrict__ partials, float* __restrict__ out1)
{
    const int t = threadIdx.x;
    if (t >= 288) return;
    const int scene = blockIdx.x >> 4;
    const int slot  = blockIdx.x & 15;
    const float* pp = partials + ((long)scene * 1024 + (long)slot * 64) * 288;
    float v = (t >= 192) ? -INFINITY : 0.f;
    for (int i = 0; i < 64; ++i) {
        float u = pp[i * 288 + t];
        v = (t >= 192) ? fmaxf(v, u) : (v + u);
    }
    out1[(long)blockIdx.x * 288 + t] = v;
}

// ---------------------------------------------------------------------------
// Kernel attn: reduce partials (4-way chunked, 384 thr) -> scene stats;
// attention MLP + softmax; analytic BN stats. Single block.
// ---------------------------------------------------------------------------
__global__ __launch_bounds__(384) void attn_kernel(
    const float* __restrict__ partials, int nper,
    const float* __restrict__ w1, const float* __restrict__ bias1,
    const float* __restrict__ w2, const float* __restrict__ bias2,
    float* __restrict__ smal)
{
    __shared__ float rS[2][4][96], rQ[2][4][96], rM[2][4][96];
    __shared__ float Sb[2][96], Qb[2][96];
    __shared__ float vecs[4][96];
    __shared__ float hid[4][48];
    __shared__ float logit[2][96];
    __shared__ float attn[2][96];
    __shared__ float red2[2][2];
    const int t = threadIdx.x;
    const int c = t % 96, j = t / 96;
    const int chunk = nper / 4;

    for (int b = 0; b < 2; ++b) {
        float s = 0.f, q = 0.f, m = -INFINITY;
        const float* pp = partials + (long)b * nper * 288 + (long)j * chunk * 288;
        for (int i = 0; i < chunk; ++i) {
            s += pp[i * 288 + c];
            q += pp[i * 288 + 96 + c];
            m = fmaxf(m, pp[i * 288 + 192 + c]);
        }
        rS[b][j][c] = s; rQ[b][j][c] = q; rM[b][j][c] = m;
    }
    __syncthreads();

    if (t < 96) {
        for (int b = 0; b < 2; ++b) {
            float s = 0.f, q = 0.f, m = -INFINITY;
            #pragma unroll
            for (int jj = 0; jj < 4; ++jj) {
                s += rS[b][jj][t];
                q += rQ[b][jj][t];
                m = fmaxf(m, rM[b][jj][t]);
            }
            Sb[b][t] = s;
            Qb[b][t] = q;
            vecs[2 * b][t]     = s * (1.0f / (float)NPB_);
            vecs[2 * b + 1][t] = m;
        }
    }
    __syncthreads();

    for (int v = 0; v < 4; ++v) {
        if (t < 48) {
            float a = bias1[t];
            for (int cc = 0; cc < 96; ++cc) a = fmaf(vecs[v][cc], w1[cc * 48 + t], a);
            hid[v][t] = fmaxf(a, 0.f);
        }
    }
    __syncthreads();

    if (t < 96) {
        for (int b = 0; b < 2; ++b) {
            float om = bias2[t], ox = bias2[t];
            for (int jj = 0; jj < 48; ++jj) {
                om = fmaf(hid[2 * b][jj],     w2[jj * 96 + t], om);
                ox = fmaf(hid[2 * b + 1][jj], w2[jj * 96 + t], ox);
            }
            logit[b][t] = fmaxf(om, 0.f) + fmaxf(ox, 0.f);
        }
    }
    __syncthreads();

    if (t < 2) {
        float mx = -INFINITY;
        for (int cc = 0; cc < 96; ++cc) mx = fmaxf(mx, logit[t][cc]);
        float s = 0.f;
        for (int cc = 0; cc < 96; ++cc) s += __expf(logit[t][cc] - mx);
        red2[t][0] = mx;
        red2[t][1] = s;
    }
    __syncthreads();
    if (t < 96) {
        for (int b = 0; b < 2; ++b)
            attn[b][t] = __expf(logit[b][t] - red2[b][0]) / red2[b][1];
    }
    __syncthreads();

    if (t < 96) {
        float a0 = attn[0][t], a1 = attn[1][t];
        const float invN = 1.0f / (float)NPTS;
        float mu = (a0 * Sb[0][t] + a1 * Sb[1][t]) * invN;
        float e2 = (a0 * a0 * Qb[0][t] + a1 * a1 * Qb[1][t]) * invN;
        float var = e2 - mu * mu;
        smal[t]       = a0;
        smal[96 + t]  = a1;
        smal[192 + t] = mu;
        smal[288 + t] = rsqrtf(var + EPS_);
    }
}

// ---------------------------------------------------------------------------
// Kernel finalize (in place on d_out which holds h):
// out = relu( relu(gamma*(h*attn - mu)*invstd + beta) + x )
// ---------------------------------------------------------------------------
__global__ __launch_bounds__(256) void final_kernel(
    const float* __restrict__ x, const float* __restrict__ smal,
    const float* __restrict__ gamma, const float* __restrict__ beta,
    float* __restrict__ out)
{
    const int nq = NPTS * 24;
    const int sceneq = NPB_ * 24;
    for (int i = blockIdx.x * 256 + threadIdx.x; i < nq; i += gridDim.x * 256) {
        const int b = (i >= sceneq) ? 1 : 0;
        const int q = i % 24;
        float4 h4 = ((const float4*)out)[i];
        float4 x4 = ((const float4*)x)[i];
        float4 a4  = ((const float4*)(smal + b * 96))[q];
        float4 mu4 = ((const float4*)(smal + 192))[q];
        float4 is4 = ((const float4*)(smal + 288))[q];
        float4 g4  = ((const float4*)gamma)[q];
        float4 be4 = ((const float4*)beta)[q];
        float4 r;
        r.x = fmaxf(fmaxf(fmaf((h4.x * a4.x - mu4.x) * is4.x, g4.x, be4.x), 0.f) + x4.x, 0.f);
        r.y = fmaxf(fmaxf(fmaf((h4.y * a4.y - mu4.y) * is4.y, g4.y, be4.y), 0.f) + x4.y, 0.f);
        r.z = fmaxf(fmaxf(fmaf((h4.z * a4.z - mu4.z) * is4.z, g4.z, be4.z), 0.f) + x4.z, 0.f);
        r.w = fmaxf(fmaxf(fmaf((h4.w * a4.w - mu4.w) * is4.w, g4.w, be4.w), 0.f) + x4.w, 0.f);
        ((float4*)out)[i] = r;
    }
}

// ---------------------------------------------------------------------------
extern "C" void kernel_launch(void* const* d_in, const int* in_sizes, int n_in,
                              void* d_out, int out_size, void* d_ws, size_t ws_size,
                              hipStream_t stream)
{
    const float* x     = (const float*)d_in[0];
    const int*   nbr   = (const int*)  d_in[1];
    const float* W     = (const float*)d_in[2];
    const float* w1    = (const float*)d_in[3];
    const float* b1    = (const float*)d_in[4];
    const float* w2    = (const float*)d_in[5];
    const float* b2    = (const float*)d_in[6];
    const float* gamma = (const float*)d_in[7];
    const float* beta  = (const float*)d_in[8];
    float* out = (float*)d_out;

    const size_t WT_BYTES   = 27UL * WTAP;                   // 497664
    const size_t XS_BYTES   = (size_t)(NPTS + 1) * 96 * 2;   // ~50.3 MB (+zero row)
    const size_t PART_BYTES = 2048UL * 288 * 4;              // 2359296
    const size_t OUT1_BYTES = 32UL * 288 * 4;                // 36864

    char* wt = (char*)d_ws;
    wprep_kernel<<<972, 256, 0, stream>>>(W, wt);

    if (ws_size >= WT_BYTES + XS_BYTES + PART_BYTES + OUT1_BYTES + 2048) {
        unsigned short* xs = (unsigned short*)(wt + WT_BYTES);
        float* partials = (float*)(wt + WT_BYTES + XS_BYTES);
        float* out1     = partials + 2048 * 288;
        float* smal     = out1 + 32 * 288;
        xprep_kernel  <<<2048, 256, 0, stream>>>(x, xs);
        conv_mfma     <<<2048, 256, 0, stream>>>(xs, nbr, wt, out, partials);
        reduce1_kernel<<<32, 384, 0, stream>>>(partials, out1);
        attn_kernel   <<<1, 384, 0, stream>>>(out1, 16, w1, b1, w2, b2, smal);
        final_kernel  <<<1024, 256, 0, stream>>>(x, smal, gamma, beta, out);
    } else {
        float* partials = (float*)(wt + WT_BYTES);
        float* smal     = partials + 1024 * 288;
        conv_mfma_cvt<<<1024, 256, 0, stream>>>(x, nbr, wt, out, partials);
        attn_kernel  <<<1, 384, 0, stream>>>(partials, 512, w1, b1, w2, b2, smal);
        final_kernel <<<1024, 256, 0, stream>>>(x, smal, gamma, beta, out);
    }
}

// Round 14
// 300.208 us; speedup vs baseline: 2.4532x; 1.0175x over previous
//
#include <hip/hip_runtime.h>
#include <math.h>

#define NPTS   262144      // B * NPB
#define NPB_   131072
#define K3_    27
#define EPS_   1e-5f
#define WTAP   18432       // bytes per tap in wt: single bf16 plane [co][ci]

typedef __attribute__((ext_vector_type(4)))  short  short4v;
typedef __attribute__((ext_vector_type(8)))  short  short8;
typedef __attribute__((ext_vector_type(8)))  __bf16 bf16x8;
typedef __attribute__((ext_vector_type(16))) float  f32x16;

__device__ __forceinline__ unsigned short f2bf(float f) {   // RNE float -> bf16 bits
    unsigned u = __builtin_bit_cast(unsigned, f);
    u += 0x7FFFu + ((u >> 16) & 1u);
    return (unsigned short)(u >> 16);
}
__device__ __forceinline__ int wswz(int co) {               // row-dependent XOR (bits 4-6)
    return ((co & 7) ^ ((co >> 3) & 3)) << 4;
}

__device__ __forceinline__ void gload_lds16(const void* g, void* l) {
    __builtin_amdgcn_global_load_lds(
        (const __attribute__((address_space(1))) unsigned int*)g,
        (__attribute__((address_space(3))) unsigned int*)l, 16, 0, 0);
}

// ---------------------------------------------------------------------------
// Kernel W-prep: W -> bf16, transposed to [co][ci], XOR-swizzled so linear
// global_load_lds staging lands in swizzled LDS layout.
// element (co,ci): byte off = (co*192 + ci*2) ^ wswz(co)
// ---------------------------------------------------------------------------
__global__ __launch_bounds__(256) void wprep_kernel(
    const float* __restrict__ W, char* __restrict__ wt)
{
    int id = blockIdx.x * 256 + threadIdx.x;
    if (id >= 27 * 96 * 96) return;
    int k = id / 9216, r = id % 9216, co = r / 96, ci = r % 96;
    float w = W[k * 9216 + ci * 96 + co];
    int swz = (co * 192 + ci * 2) ^ wswz(co);
    *(unsigned short*)(wt + (long)k * WTAP + swz) = f2bf(w);
}

// ---------------------------------------------------------------------------
// Kernel X-prep: x[N][96] f32 -> xs[N][96] bf16, plus a zero row at xs[NPTS]
// used for invalid neighbor indices.
// ---------------------------------------------------------------------------
__global__ __launch_bounds__(256) void xprep_kernel(
    const float* __restrict__ x, unsigned short* __restrict__ xs)
{
    const long nquads = (long)NPTS * 24;
    for (long id = (long)blockIdx.x * 256 + threadIdx.x; id < nquads;
         id += (long)gridDim.x * 256) {
        long n = id / 24;
        int  c = (int)(id % 24) * 4;
        float4 v = ((const float4*)x)[id];
        short4v hv = { (short)f2bf(v.x), (short)f2bf(v.y),
                       (short)f2bf(v.z), (short)f2bf(v.w) };
        *(short4v*)(xs + n * 96 + c) = hv;
    }
    if (blockIdx.x == 0 && threadIdx.x < 12) {
        short8 z = {0,0,0,0,0,0,0,0};
        *(short8*)(xs + (long)NPTS * 96 + threadIdx.x * 8) = z;
    }
}

// ---------------------------------------------------------------------------
// conv helpers
// ---------------------------------------------------------------------------
__device__ __forceinline__ void mfma_step1(
    f32x16 acc[3], short8 a,
    const char* wbase, int cioff2, const int* cobase, int xorv)
{
    bf16x8 av = __builtin_bit_cast(bf16x8, a);
    #pragma unroll
    for (int n = 0; n < 3; ++n) {
        int ad = (cobase[n] + cioff2) ^ xorv;
        bf16x8 bh = __builtin_bit_cast(bf16x8, *(const short8*)(wbase + ad));
        acc[n] = __builtin_amdgcn_mfma_f32_32x32x16_bf16(av, bh, acc[n], 0, 0, 0);
    }
}

__device__ __forceinline__ void stage_w256(const char* g, char* lp, int tid)
{
    #pragma unroll
    for (int i = 0; i < 4; ++i)
        gload_lds16(g + tid * 16 + i * 4096, lp + tid * 16 + i * 4096);
    if (tid < 128)
        gload_lds16(g + 16384 + tid * 16, lp + 16384 + tid * 16);
}

__device__ __forceinline__ void stage_w512(const char* g, char* lp, int tid)
{
    // 18432 B = 512*16*2 + 128*16
    #pragma unroll
    for (int i = 0; i < 2; ++i)
        gload_lds16(g + tid * 16 + i * 8192, lp + tid * 16 + i * 8192);
    if (tid < 128)
        gload_lds16(g + 16384 + tid * 16, lp + 16384 + tid * 16);
}

// ---------------------------------------------------------------------------
// Kernel conv (v9): pure bf16, 1 row per lane, 512 thr / 8 waves sharing one
// W double-buffer (36 KB LDS) -> 4 blocks/CU x 8 waves = 32 waves/CU (full
// occupancy) for gather TLP. 256 rows per block, grid 1024.
// 6-slot A ring + raw s_barrier + counted vmcnt(5).
// ---------------------------------------------------------------------------
__global__ __launch_bounds__(512, 4) void conv_mfma(
    const unsigned short* __restrict__ xs, const int* __restrict__ nbr,
    const char* __restrict__ wt, float* __restrict__ hout,
    float* __restrict__ partials)
{
    __shared__ __align__(16) char wlds[2][WTAP];   // 36 KB total

    const int tid = threadIdx.x;
    const int wv  = tid >> 6;                 // 0..7
    const int l   = tid & 63;
    const int l31 = l & 31;
    const int lh  = l >> 5;
    const int blockM = blockIdx.x * 256;
    const int row0 = blockM + wv * 32 + l31;

    f32x16 acc[3] = {};
    const int xorv = wswz(l31);
    int cobase[3];
    #pragma unroll
    for (int n = 0; n < 3; ++n) cobase[n] = (n * 32 + l31) * 192;

    // prologue: stage tap-0 W; tap-0/1 indices; prime slots 0..4
    stage_w512(wt, wlds[0], tid);
    int idx0 = nbr[row0 * 27];
    int jdx0 = nbr[row0 * 27 + 1];
    const unsigned short* b0 = xs + (long)(idx0 >= 0 ? idx0 : NPTS) * 96;

    short8 abuf[6];                          // 6-slot ring, statically indexed
    abuf[0] = *(const short8*)(b0 +  0 + lh * 8);
    abuf[1] = *(const short8*)(b0 + 16 + lh * 8);
    abuf[2] = *(const short8*)(b0 + 32 + lh * 8);
    abuf[3] = *(const short8*)(b0 + 48 + lh * 8);
    abuf[4] = *(const short8*)(b0 + 64 + lh * 8);

    #pragma unroll 1
    for (int k = 0; k < 27; ++k) {
        // boundary: vmcnt(5) retires all but the 5 newest VMEM ops (the
        // prefetched A refills) -> this wave's W LDS-writes complete before
        // the raw barrier; A pipeline stays live across it.
        __builtin_amdgcn_sched_barrier(0);
        asm volatile("s_waitcnt vmcnt(5)" ::: "memory");
        __builtin_amdgcn_sched_barrier(0);
        __builtin_amdgcn_s_barrier();
        __builtin_amdgcn_sched_barrier(0);

        const char* wbase = wlds[k & 1];
        if (k < 26)                           // stage W(k+1)
            stage_w512(wt + (long)(k + 1) * WTAP, wlds[(k + 1) & 1], tid);
        const int kn = (k + 2 <= 26) ? (k + 2) : 26;
        int t0 = nbr[row0 * 27 + kn];         // 2-tap-ahead index prefetch
        const unsigned short* nb0 = xs + (long)(jdx0 >= 0 ? jdx0 : NPTS) * 96;

        // step s consumes slot s; refills go to next tap's steps 0..4
        abuf[5] = *(const short8*)(b0 + 80 + lh * 8);
        mfma_step1(acc, abuf[0], wbase,   0 + lh * 16, cobase, xorv);
        abuf[0] = *(const short8*)(nb0 +  0 + lh * 8);
        mfma_step1(acc, abuf[1], wbase,  32 + lh * 16, cobase, xorv);
        abuf[1] = *(const short8*)(nb0 + 16 + lh * 8);
        mfma_step1(acc, abuf[2], wbase,  64 + lh * 16, cobase, xorv);
        abuf[2] = *(const short8*)(nb0 + 32 + lh * 8);
        mfma_step1(acc, abuf[3], wbase,  96 + lh * 16, cobase, xorv);
        abuf[3] = *(const short8*)(nb0 + 48 + lh * 8);
        mfma_step1(acc, abuf[4], wbase, 128 + lh * 16, cobase, xorv);
        abuf[4] = *(const short8*)(nb0 + 64 + lh * 8);
        mfma_step1(acc, abuf[5], wbase, 160 + lh * 16, cobase, xorv);

        b0 = nb0;
        jdx0 = t0;
    }

    // ---- write h (C/D layout: col = lane&31, row = (r&3) + 8*(r>>2) + 4*lh)
    #pragma unroll
    for (int n = 0; n < 3; ++n)
        #pragma unroll
        for (int r = 0; r < 16; ++r) {
            int rw = (r & 3) + 8 * (r >> 2) + 4 * lh;
            hout[(long)(blockM + wv * 32 + rw) * 96 + n * 32 + l31] = acc[n][r];
        }

    // ---- fused per-block channel stats (sum / sumsq / max)
    float sv[3], qv[3], mv[3];
    #pragma unroll
    for (int n = 0; n < 3; ++n) { sv[n] = 0.f; qv[n] = 0.f; mv[n] = -INFINITY; }
    #pragma unroll
    for (int n = 0; n < 3; ++n)
        #pragma unroll
        for (int r = 0; r < 16; ++r) {
            float v = acc[n][r];
            sv[n] += v;
            qv[n] = fmaf(v, v, qv[n]);
            mv[n] = fmaxf(mv[n], v);
        }
    #pragma unroll
    for (int n = 0; n < 3; ++n) {
        sv[n] += __shfl_xor(sv[n], 32);
        qv[n] += __shfl_xor(qv[n], 32);
        mv[n] = fmaxf(mv[n], __shfl_xor(mv[n], 32));
    }
    // stats scratch aliased into wlds (W dead after K-loop): 8*3*32*3 floats
    float (*red)[3][32][3] = (float (*)[3][32][3])(&wlds[0][0]);
    __syncthreads();
    if (lh == 0) {
        #pragma unroll
        for (int n = 0; n < 3; ++n) {
            red[wv][n][l31][0] = sv[n];
            red[wv][n][l31][1] = qv[n];
            red[wv][n][l31][2] = mv[n];
        }
    }
    __syncthreads();
    if (tid < 96) {
        int n = tid >> 5, c = tid & 31;
        float S = 0.f, Q = 0.f, M = -INFINITY;
        #pragma unroll
        for (int w = 0; w < 8; ++w) {
            S += red[w][n][c][0];
            Q += red[w][n][c][1];
            M = fmaxf(M, red[w][n][c][2]);
        }
        float* op = partials + (long)blockIdx.x * 288;
        op[tid] = S; op[96 + tid] = Q; op[192 + tid] = M;
    }
}

// ---------------------------------------------------------------------------
// Fallback conv (fp32 source, in-kernel bf16 convert, single-term) used when
// ws_size can't hold xs. Same numerics as main path. 1024 blocks x 256 thr.
// ---------------------------------------------------------------------------
__global__ __launch_bounds__(256, 2) void conv_mfma_cvt(
    const float* __restrict__ x, const int* __restrict__ nbr,
    const char* __restrict__ wt, float* __restrict__ hout,
    float* __restrict__ partials)
{
    __shared__ __align__(16) char wlds[WTAP];
    __shared__ float red[4][3][32][3];

    const int tid = threadIdx.x;
    const int wv  = tid >> 6;
    const int l   = tid & 63;
    const int l31 = l & 31;
    const int lh  = l >> 5;
    const int blockM = blockIdx.x * 256;
    const int row0 = blockM + wv * 64 + l31;
    const int row1 = row0 + 32;

    f32x16 acc[2][3] = {};
    const int xorv = wswz(l31);
    int cobase[3];
    #pragma unroll
    for (int n = 0; n < 3; ++n) cobase[n] = (n * 32 + l31) * 192;

    int idx0 = nbr[row0 * 27];
    int idx1 = nbr[row1 * 27];

    #pragma unroll 1
    for (int k = 0; k < 27; ++k) {
        __syncthreads();
        stage_w256(wt + (long)k * WTAP, wlds, tid);
        __syncthreads();

        #pragma unroll
        for (int s = 0; s < 6; ++s) {
            float4 q0 = make_float4(0,0,0,0), q1 = q0, p0 = q0, p1 = q0;
            if (idx0 >= 0) {
                q0 = *(const float4*)(x + (long)idx0 * 96 + s * 16 + lh * 8);
                q1 = *(const float4*)(x + (long)idx0 * 96 + s * 16 + lh * 8 + 4);
            }
            if (idx1 >= 0) {
                p0 = *(const float4*)(x + (long)idx1 * 96 + s * 16 + lh * 8);
                p1 = *(const float4*)(x + (long)idx1 * 96 + s * 16 + lh * 8 + 4);
            }
            short8 ab0, ab1;
            float a0[8] = {q0.x,q0.y,q0.z,q0.w,q1.x,q1.y,q1.z,q1.w};
            float a1[8] = {p0.x,p0.y,p0.z,p0.w,p1.x,p1.y,p1.z,p1.w};
            #pragma unroll
            for (int j = 0; j < 8; ++j) {
                ab0[j] = (short)f2bf(a0[j]);
                ab1[j] = (short)f2bf(a1[j]);
            }
            bf16x8 av0 = __builtin_bit_cast(bf16x8, ab0);
            bf16x8 av1 = __builtin_bit_cast(bf16x8, ab1);
            const int cioff2 = s * 32 + lh * 16;
            #pragma unroll
            for (int n = 0; n < 3; ++n) {
                int ad = (cobase[n] + cioff2) ^ xorv;
                bf16x8 bh = __builtin_bit_cast(bf16x8, *(const short8*)(wlds + ad));
                acc[0][n] = __builtin_amdgcn_mfma_f32_32x32x16_bf16(av0, bh, acc[0][n], 0, 0, 0);
                acc[1][n] = __builtin_amdgcn_mfma_f32_32x32x16_bf16(av1, bh, acc[1][n], 0, 0, 0);
            }
        }
        if (k < 26) {
            idx0 = nbr[row0 * 27 + k + 1];
            idx1 = nbr[row1 * 27 + k + 1];
        }
    }

    #pragma unroll
    for (int ms = 0; ms < 2; ++ms)
        #pragma unroll
        for (int n = 0; n < 3; ++n)
            #pragma unroll
            for (int r = 0; r < 16; ++r) {
                int rw = (r & 3) + 8 * (r >> 2) + 4 * lh;
                hout[(long)(blockM + wv * 64 + ms * 32 + rw) * 96 + n * 32 + l31] = acc[ms][n][r];
            }

    float sv[3], qv[3], mv[3];
    #pragma unroll
    for (int n = 0; n < 3; ++n) { sv[n] = 0.f; qv[n] = 0.f; mv[n] = -INFINITY; }
    #pragma unroll
    for (int ms = 0; ms < 2; ++ms)
        #pragma unroll
        for (int n = 0; n < 3; ++n)
            #pragma unroll
            for (int r = 0; r < 16; ++r) {
                float v = acc[ms][n][r];
                sv[n] += v; qv[n] = fmaf(v, v, qv[n]); mv[n] = fmaxf(mv[n], v);
            }
    #pragma unroll
    for (int n = 0; n < 3; ++n) {
        sv[n] += __shfl_xor(sv[n], 32);
        qv[n] += __shfl_xor(qv[n], 32);
        mv[n] = fmaxf(mv[n], __shfl_xor(mv[n], 32));
    }
    if (lh == 0) {
        #pragma unroll
        for (int n = 0; n < 3; ++n) {
            red[wv][n][l31][0] = sv[n];
            red[wv][n][l31][1] = qv[n];
            red[wv][n][l31][2] = mv[n];
        }
    }
    __syncthreads();
    if (tid < 96) {
        int n = tid >> 5, c = tid & 31;
        float S = 0.f, Q = 0.f, M = -INFINITY;
        #pragma unroll
        for (int w = 0; w < 4; ++w) {
            S += red[w][n][c][0];
            Q += red[w][n][c][1];
            M = fmaxf(M, red[w][n][c][2]);
        }
        float* op = partials + (long)blockIdx.x * 288;
        op[tid] = S; op[96 + tid] = Q; op[192 + tid] = M;
    }
}

// ---------------------------------------------------------------------------
// Kernel reduce1: collapse 1024 partial rows -> 32 (16 per scene, 32 rows
// each). cols 0..191 sum, 192..287 max.
// ---------------------------------------------------------------------------
__global__ __launch_bounds__(384) void reduce1_kernel(
    const float* __restrict__ partials, float* __restrict__ out1)
{
    const int t = threadIdx.x;
    if (t >= 288) return;
    const int scene = blockIdx.x >> 4;
    const int slot  = blockIdx.x & 15;
    const float* pp = partials + ((long)scene * 512 + (long)slot * 32) * 288;
    float v = (t >= 192) ? -INFINITY : 0.f;
    for (int i = 0; i < 32; ++i) {
        float u = pp[i * 288 + t];
        v = (t >= 192) ? fmaxf(v, u) : (v + u);
    }
    out1[(long)blockIdx.x * 288 + t] = v;
}

// ---------------------------------------------------------------------------
// Kernel attn: reduce partials (4-way chunked, 384 thr) -> scene stats;
// attention MLP + softmax; analytic BN stats. Single block.
// ---------------------------------------------------------------------------
__global__ __launch_bounds__(384) void attn_kernel(
    const float* __restrict__ partials, int nper,
    const float* __restrict__ w1, const float* __restrict__ bias1,
    const float* __restrict__ w2, const float* __restrict__ bias2,
    float* __restrict__ smal)
{
    __shared__ float rS[2][4][96], rQ[2][4][96], rM[2][4][96];
    __shared__ float Sb[2][96], Qb[2][96];
    __shared__ float vecs[4][96];
    __shared__ float hid[4][48];
    __shared__ float logit[2][96];
    __shared__ float attn[2][96];
    __shared__ float red2[2][2];
    const int t = threadIdx.x;
    const int c = t % 96, j = t / 96;
    const int chunk = nper / 4;

    for (int b = 0; b < 2; ++b) {
        float s = 0.f, q = 0.f, m = -INFINITY;
        const float* pp = partials + (long)b * nper * 288 + (long)j * chunk * 288;
        for (int i = 0; i < chunk; ++i) {
            s += pp[i * 288 + c];
            q += pp[i * 288 + 96 + c];
            m = fmaxf(m, pp[i * 288 + 192 + c]);
        }
        rS[b][j][c] = s; rQ[b][j][c] = q; rM[b][j][c] = m;
    }
    __syncthreads();

    if (t < 96) {
        for (int b = 0; b < 2; ++b) {
            float s = 0.f, q = 0.f, m = -INFINITY;
            #pragma unroll
            for (int jj = 0; jj < 4; ++jj) {
                s += rS[b][jj][t];
                q += rQ[b][jj][t];
                m = fmaxf(m, rM[b][jj][t]);
            }
            Sb[b][t] = s;
            Qb[b][t] = q;
            vecs[2 * b][t]     = s * (1.0f / (float)NPB_);
            vecs[2 * b + 1][t] = m;
        }
    }
    __syncthreads();

    for (int v = 0; v < 4; ++v) {
        if (t < 48) {
            float a = bias1[t];
            for (int cc = 0; cc < 96; ++cc) a = fmaf(vecs[v][cc], w1[cc * 48 + t], a);
            hid[v][t] = fmaxf(a, 0.f);
        }
    }
    __syncthreads();

    if (t < 96) {
        for (int b = 0; b < 2; ++b) {
            float om = bias2[t], ox = bias2[t];
            for (int jj = 0; jj < 48; ++jj) {
                om = fmaf(hid[2 * b][jj],     w2[jj * 96 + t], om);
                ox = fmaf(hid[2 * b + 1][jj], w2[jj * 96 + t], ox);
            }
            logit[b][t] = fmaxf(om, 0.f) + fmaxf(ox, 0.f);
        }
    }
    __syncthreads();

    if (t < 2) {
        float mx = -INFINITY;
        for (int cc = 0; cc < 96; ++cc) mx = fmaxf(mx, logit[t][cc]);
        float s = 0.f;
        for (int cc = 0; cc < 96; ++cc) s += __expf(logit[t][cc] - mx);
        red2[t][0] = mx;
        red2[t][1] = s;
    }
    __syncthreads();
    if (t < 96) {
        for (int b = 0; b < 2; ++b)
            attn[b][t] = __expf(logit[b][t] - red2[b][0]) / red2[b][1];
    }
    __syncthreads();

    if (t < 96) {
        float a0 = attn[0][t], a1 = attn[1][t];
        const float invN = 1.0f / (float)NPTS;
        float mu = (a0 * Sb[0][t] + a1 * Sb[1][t]) * invN;
        float e2 = (a0 * a0 * Qb[0][t] + a1 * a1 * Qb[1][t]) * invN;
        float var = e2 - mu * mu;
        smal[t]       = a0;
        smal[96 + t]  = a1;
        smal[192 + t] = mu;
        smal[288 + t] = rsqrtf(var + EPS_);
    }
}

// ---------------------------------------------------------------------------
// Kernel finalize (in place on d_out which holds h):
// out = relu( relu(gamma*(h*attn - mu)*invstd + beta) + x )
// ---------------------------------------------------------------------------
__global__ __launch_bounds__(256) void final_kernel(
    const float* __restrict__ x, const float* __restrict__ smal,
    const float* __restrict__ gamma, const float* __restrict__ beta,
    float* __restrict__ out)
{
    const int nq = NPTS * 24;
    const int sceneq = NPB_ * 24;
    for (int i = blockIdx.x * 256 + threadIdx.x; i < nq; i += gridDim.x * 256) {
        const int b = (i >= sceneq) ? 1 : 0;
        const int q = i % 24;
        float4 h4 = ((const float4*)out)[i];
        float4 x4 = ((const float4*)x)[i];
        float4 a4  = ((const float4*)(smal + b * 96))[q];
        float4 mu4 = ((const float4*)(smal + 192))[q];
        float4 is4 = ((const float4*)(smal + 288))[q];
        float4 g4  = ((const float4*)gamma)[q];
        float4 be4 = ((const float4*)beta)[q];
        float4 r;
        r.x = fmaxf(fmaxf(fmaf((h4.x * a4.x - mu4.x) * is4.x, g4.x, be4.x), 0.f) + x4.x, 0.f);
        r.y = fmaxf(fmaxf(fmaf((h4.y * a4.y - mu4.y) * is4.y, g4.y, be4.y), 0.f) + x4.y, 0.f);
        r.z = fmaxf(fmaxf(fmaf((h4.z * a4.z - mu4.z) * is4.z, g4.z, be4.z), 0.f) + x4.z, 0.f);
        r.w = fmaxf(fmaxf(fmaf((h4.w * a4.w - mu4.w) * is4.w, g4.w, be4.w), 0.f) + x4.w, 0.f);
        ((float4*)out)[i] = r;
    }
}

// ---------------------------------------------------------------------------
extern "C" void kernel_launch(void* const* d_in, const int* in_sizes, int n_in,
                              void* d_out, int out_size, void* d_ws, size_t ws_size,
                              hipStream_t stream)
{
    const float* x     = (const float*)d_in[0];
    const int*   nbr   = (const int*)  d_in[1];
    const float* W     = (const float*)d_in[2];
    const float* w1    = (const float*)d_in[3];
    const float* b1    = (const float*)d_in[4];
    const float* w2    = (const float*)d_in[5];
    const float* b2    = (const float*)d_in[6];
    const float* gamma = (const float*)d_in[7];
    const float* beta  = (const float*)d_in[8];
    float* out = (float*)d_out;

    const size_t WT_BYTES   = 27UL * WTAP;                   // 497664
    const size_t XS_BYTES   = (size_t)(NPTS + 1) * 96 * 2;   // ~50.3 MB (+zero row)
    const size_t PART_BYTES = 1024UL * 288 * 4;              // 1179648
    const size_t OUT1_BYTES = 32UL * 288 * 4;                // 36864

    char* wt = (char*)d_ws;
    wprep_kernel<<<972, 256, 0, stream>>>(W, wt);

    if (ws_size >= WT_BYTES + XS_BYTES + PART_BYTES + OUT1_BYTES + 2048) {
        unsigned short* xs = (unsigned short*)(wt + WT_BYTES);
        float* partials = (float*)(wt + WT_BYTES + XS_BYTES);
        float* out1     = partials + 1024 * 288;
        float* smal     = out1 + 32 * 288;
        xprep_kernel  <<<2048, 256, 0, stream>>>(x, xs);
        conv_mfma     <<<1024, 512, 0, stream>>>(xs, nbr, wt, out, partials);
        reduce1_kernel<<<32, 384, 0, stream>>>(partials, out1);
        attn_kernel   <<<1, 384, 0, stream>>>(out1, 16, w1, b1, w2, b2, smal);
        final_kernel  <<<1024, 256, 0, stream>>>(x, smal, gamma, beta, out);
    } else {
        float* partials = (float*)(wt + WT_BYTES);
        float* smal     = partials + 1024 * 288;
        conv_mfma_cvt<<<1024, 256, 0, stream>>>(x, nbr, wt, out, partials);
        attn_kernel  <<<1, 384, 0, stream>>>(partials, 512, w1, b1, w2, b2, smal);
        final_kernel <<<1024, 256, 0, stream>>>(x, smal, gamma, beta, out);
    }
}

// Round 17
// 296.575 us; speedup vs baseline: 2.4832x; 1.0122x over previous
//
#include <hip/hip_runtime.h>
#include <math.h>

#define NPTS   262144      // B * NPB
#define NPB_   131072
#define K3_    27
#define EPS_   1e-5f
#define WTAP   18432       // bytes per tap in wt: single bf16 plane [co][ci]

typedef __attribute__((ext_vector_type(4)))  short  short4v;
typedef __attribute__((ext_vector_type(8)))  short  short8;
typedef __attribute__((ext_vector_type(8)))  __bf16 bf16x8;
typedef __attribute__((ext_vector_type(16))) float  f32x16;

__device__ __forceinline__ unsigned short f2bf(float f) {   // RNE float -> bf16 bits
    unsigned u = __builtin_bit_cast(unsigned, f);
    u += 0x7FFFu + ((u >> 16) & 1u);
    return (unsigned short)(u >> 16);
}
__device__ __forceinline__ int wswz(int co) {               // row-dependent XOR (bits 4-6)
    return ((co & 7) ^ ((co >> 3) & 3)) << 4;
}

__device__ __forceinline__ void gload_lds16(const void* g, void* l) {
    __builtin_amdgcn_global_load_lds(
        (const __attribute__((address_space(1))) unsigned int*)g,
        (__attribute__((address_space(3))) unsigned int*)l, 16, 0, 0);
}

// ---------------------------------------------------------------------------
// Kernel W-prep: W -> bf16, transposed to [co][ci], XOR-swizzled so linear
// global_load_lds staging lands in swizzled LDS layout.
// element (co,ci): byte off = (co*192 + ci*2) ^ wswz(co)
// ---------------------------------------------------------------------------
__global__ __launch_bounds__(256) void wprep_kernel(
    const float* __restrict__ W, char* __restrict__ wt)
{
    int id = blockIdx.x * 256 + threadIdx.x;
    if (id >= 27 * 96 * 96) return;
    int k = id / 9216, r = id % 9216, co = r / 96, ci = r % 96;
    float w = W[k * 9216 + ci * 96 + co];
    int swz = (co * 192 + ci * 2) ^ wswz(co);
    *(unsigned short*)(wt + (long)k * WTAP + swz) = f2bf(w);
}

// ---------------------------------------------------------------------------
// Kernel X-prep: x[N][96] f32 -> xs[N][96] bf16, plus a zero row at xs[NPTS]
// used for invalid neighbor indices.
// ---------------------------------------------------------------------------
__global__ __launch_bounds__(256) void xprep_kernel(
    const float* __restrict__ x, unsigned short* __restrict__ xs)
{
    const long nquads = (long)NPTS * 24;
    for (long id = (long)blockIdx.x * 256 + threadIdx.x; id < nquads;
         id += (long)gridDim.x * 256) {
        long n = id / 24;
        int  c = (int)(id % 24) * 4;
        float4 v = ((const float4*)x)[id];
        short4v hv = { (short)f2bf(v.x), (short)f2bf(v.y),
                       (short)f2bf(v.z), (short)f2bf(v.w) };
        *(short4v*)(xs + n * 96 + c) = hv;
    }
    if (blockIdx.x == 0 && threadIdx.x < 12) {
        short8 z = {0,0,0,0,0,0,0,0};
        *(short8*)(xs + (long)NPTS * 96 + threadIdx.x * 8) = z;
    }
}

// ---------------------------------------------------------------------------
// conv helpers
// ---------------------------------------------------------------------------
__device__ __forceinline__ void mfma_step1(
    f32x16 acc[3], short8 a,
    const char* wbase, int cioff2, const int* cobase, int xorv)
{
    bf16x8 av = __builtin_bit_cast(bf16x8, a);
    #pragma unroll
    for (int n = 0; n < 3; ++n) {
        int ad = (cobase[n] + cioff2) ^ xorv;
        bf16x8 bh = __builtin_bit_cast(bf16x8, *(const short8*)(wbase + ad));
        acc[n] = __builtin_amdgcn_mfma_f32_32x32x16_bf16(av, bh, acc[n], 0, 0, 0);
    }
}

__device__ __forceinline__ void stage_w256(const char* g, char* lp, int tid)
{
    #pragma unroll
    for (int i = 0; i < 4; ++i)
        gload_lds16(g + tid * 16 + i * 4096, lp + tid * 16 + i * 4096);
    if (tid < 128)
        gload_lds16(g + 16384 + tid * 16, lp + 16384 + tid * 16);
}

__device__ __forceinline__ void stage_w512(const char* g, char* lp, int tid)
{
    // 18432 B = 512*16*2 + 128*16
    #pragma unroll
    for (int i = 0; i < 2; ++i)
        gload_lds16(g + tid * 16 + i * 8192, lp + tid * 16 + i * 8192);
    if (tid < 128)
        gload_lds16(g + 16384 + tid * 16, lp + 16384 + tid * 16);
}

// ---------------------------------------------------------------------------
// Kernel conv (v10): pure bf16, 1 row per lane, 512 thr / 8 waves, W double-
// buffer in 36 KB LDS, grid 1024 (4 blocks/CU). TWO 6-slot A rings (slA/slB,
// static parity) = 2-tap lookahead, ~11 gathers in flight per wave.
// Boundary: raw s_barrier + vmcnt(7) (1 nbr + 6 refills issued after the
// W staging each tap -> staging retired, A pipeline live across barrier).
// ---------------------------------------------------------------------------
__global__ __launch_bounds__(512, 4) void conv_mfma(
    const unsigned short* __restrict__ xs, const int* __restrict__ nbr,
    const char* __restrict__ wt, float* __restrict__ hout,
    float* __restrict__ partials)
{
    __shared__ __align__(16) char wlds[2][WTAP];   // 36 KB total

    const int tid = threadIdx.x;
    const int wv  = tid >> 6;                 // 0..7
    const int l   = tid & 63;
    const int l31 = l & 31;
    const int lh  = l >> 5;
    const int blockM = blockIdx.x * 256;
    const int row0 = blockM + wv * 32 + l31;

    f32x16 acc[3] = {};
    const int xorv = wswz(l31);
    int cobase[3];
    #pragma unroll
    for (int n = 0; n < 3; ++n) cobase[n] = (n * 32 + l31) * 192;

    // prologue: stage tap-0 W; idx for taps 0,1,2; fill both rings
    stage_w512(wt, wlds[0], tid);
    int i0 = nbr[row0 * 27];
    int i1 = nbr[row0 * 27 + 1];
    int jdx = nbr[row0 * 27 + 2];            // idx for tap 2 (value held)
    const unsigned short* p0 = xs + (long)(i0 >= 0 ? i0 : NPTS) * 96;
    const unsigned short* p1 = xs + (long)(i1 >= 0 ? i1 : NPTS) * 96;

    short8 slA[6], slB[6];                   // two static 6-slot rings
    #pragma unroll
    for (int s = 0; s < 6; ++s) slA[s] = *(const short8*)(p0 + s * 16 + lh * 8);
    #pragma unroll
    for (int s = 0; s < 6; ++s) slB[s] = *(const short8*)(p1 + s * 16 + lh * 8);

// TAP(k): consume CONS (loaded 2 taps ago), reissue CONS for tap k+2 from
// jdx's row; prefetch idx for tap k+3 into jdx.
#define TAP(kv, CONS) do {                                                    \
    __builtin_amdgcn_sched_barrier(0);                                        \
    asm volatile("s_waitcnt vmcnt(7)" ::: "memory");                          \
    __builtin_amdgcn_sched_barrier(0);                                        \
    __builtin_amdgcn_s_barrier();                                             \
    __builtin_amdgcn_sched_barrier(0);                                        \
    const char* wbase = wlds[(kv) & 1];                                       \
    if ((kv) < 26)                                                            \
        stage_w512(wt + (long)((kv) + 1) * WTAP, wlds[((kv) + 1) & 1], tid);  \
    const int kn_ = ((kv) + 3 <= 26) ? (kv) + 3 : 26;                         \
    int tn_ = nbr[row0 * 27 + kn_];                                           \
    const unsigned short* nb_ = xs + (long)(jdx >= 0 ? jdx : NPTS) * 96;      \
    short8 t_;                                                                \
    t_ = CONS[0]; CONS[0] = *(const short8*)(nb_ +  0 + lh * 8);              \
    mfma_step1(acc, t_, wbase,   0 + lh * 16, cobase, xorv);                  \
    t_ = CONS[1]; CONS[1] = *(const short8*)(nb_ + 16 + lh * 8);              \
    mfma_step1(acc, t_, wbase,  32 + lh * 16, cobase, xorv);                  \
    t_ = CONS[2]; CONS[2] = *(const short8*)(nb_ + 32 + lh * 8);              \
    mfma_step1(acc, t_, wbase,  64 + lh * 16, cobase, xorv);                  \
    t_ = CONS[3]; CONS[3] = *(const short8*)(nb_ + 48 + lh * 8);              \
    mfma_step1(acc, t_, wbase,  96 + lh * 16, cobase, xorv);                  \
    t_ = CONS[4]; CONS[4] = *(const short8*)(nb_ + 64 + lh * 8);              \
    mfma_step1(acc, t_, wbase, 128 + lh * 16, cobase, xorv);                  \
    t_ = CONS[5]; CONS[5] = *(const short8*)(nb_ + 80 + lh * 8);              \
    mfma_step1(acc, t_, wbase, 160 + lh * 16, cobase, xorv);                  \
    jdx = tn_;                                                                \
} while (0)

    #pragma unroll 1
    for (int kk = 0; kk < 13; ++kk) {
        TAP(2 * kk,     slA);
        TAP(2 * kk + 1, slB);
    }
    TAP(26, slA);
#undef TAP

    // ---- write h (C/D layout: col = lane&31, row = (r&3) + 8*(r>>2) + 4*lh)
    #pragma unroll
    for (int n = 0; n < 3; ++n)
        #pragma unroll
        for (int r = 0; r < 16; ++r) {
            int rw = (r & 3) + 8 * (r >> 2) + 4 * lh;
            hout[(long)(blockM + wv * 32 + rw) * 96 + n * 32 + l31] = acc[n][r];
        }

    // ---- fused per-block channel stats (sum / sumsq / max)
    float sv[3], qv[3], mv[3];
    #pragma unroll
    for (int n = 0; n < 3; ++n) { sv[n] = 0.f; qv[n] = 0.f; mv[n] = -INFINITY; }
    #pragma unroll
    for (int n = 0; n < 3; ++n)
        #pragma unroll
        for (int r = 0; r < 16; ++r) {
            float v = acc[n][r];
            sv[n] += v;
            qv[n] = fmaf(v, v, qv[n]);
            mv[n] = fmaxf(mv[n], v);
        }
    #pragma unroll
    for (int n = 0; n < 3; ++n) {
        sv[n] += __shfl_xor(sv[n], 32);
        qv[n] += __shfl_xor(qv[n], 32);
        mv[n] = fmaxf(mv[n], __shfl_xor(mv[n], 32));
    }
    // stats scratch aliased into wlds (W dead after K-loop): 8*3*32*3 floats
    float (*red)[3][32][3] = (float (*)[3][32][3])(&wlds[0][0]);
    __syncthreads();
    if (lh == 0) {
        #pragma unroll
        for (int n = 0; n < 3; ++n) {
            red[wv][n][l31][0] = sv[n];
            red[wv][n][l31][1] = qv[n];
            red[wv][n][l31][2] = mv[n];
        }
    }
    __syncthreads();
    if (tid < 96) {
        int n = tid >> 5, c = tid & 31;
        float S = 0.f, Q = 0.f, M = -INFINITY;
        #pragma unroll
        for (int w = 0; w < 8; ++w) {
            S += red[w][n][c][0];
            Q += red[w][n][c][1];
            M = fmaxf(M, red[w][n][c][2]);
        }
        float* op = partials + (long)blockIdx.x * 288;
        op[tid] = S; op[96 + tid] = Q; op[192 + tid] = M;
    }
}

// ---------------------------------------------------------------------------
// Fallback conv (fp32 source, in-kernel bf16 convert, single-term) used when
// ws_size can't hold xs. Same numerics as main path. 1024 blocks x 256 thr.
// ---------------------------------------------------------------------------
__global__ __launch_bounds__(256, 2) void conv_mfma_cvt(
    const float* __restrict__ x, const int* __restrict__ nbr,
    const char* __restrict__ wt, float* __restrict__ hout,
    float* __restrict__ partials)
{
    __shared__ __align__(16) char wlds[WTAP];
    __shared__ float red[4][3][32][3];

    const int tid = threadIdx.x;
    const int wv  = tid >> 6;
    const int l   = tid & 63;
    const int l31 = l & 31;
    const int lh  = l >> 5;
    const int blockM = blockIdx.x * 256;
    const int row0 = blockM + wv * 64 + l31;
    const int row1 = row0 + 32;

    f32x16 acc[2][3] = {};
    const int xorv = wswz(l31);
    int cobase[3];
    #pragma unroll
    for (int n = 0; n < 3; ++n) cobase[n] = (n * 32 + l31) * 192;

    int idx0 = nbr[row0 * 27];
    int idx1 = nbr[row1 * 27];

    #pragma unroll 1
    for (int k = 0; k < 27; ++k) {
        __syncthreads();
        stage_w256(wt + (long)k * WTAP, wlds, tid);
        __syncthreads();

        #pragma unroll
        for (int s = 0; s < 6; ++s) {
            float4 q0 = make_float4(0,0,0,0), q1 = q0, p0 = q0, p1 = q0;
            if (idx0 >= 0) {
                q0 = *(const float4*)(x + (long)idx0 * 96 + s * 16 + lh * 8);
                q1 = *(const float4*)(x + (long)idx0 * 96 + s * 16 + lh * 8 + 4);
            }
            if (idx1 >= 0) {
                p0 = *(const float4*)(x + (long)idx1 * 96 + s * 16 + lh * 8);
                p1 = *(const float4*)(x + (long)idx1 * 96 + s * 16 + lh * 8 + 4);
            }
            short8 ab0, ab1;
            float a0[8] = {q0.x,q0.y,q0.z,q0.w,q1.x,q1.y,q1.z,q1.w};
            float a1[8] = {p0.x,p0.y,p0.z,p0.w,p1.x,p1.y,p1.z,p1.w};
            #pragma unroll
            for (int j = 0; j < 8; ++j) {
                ab0[j] = (short)f2bf(a0[j]);
                ab1[j] = (short)f2bf(a1[j]);
            }
            bf16x8 av0 = __builtin_bit_cast(bf16x8, ab0);
            bf16x8 av1 = __builtin_bit_cast(bf16x8, ab1);
            const int cioff2 = s * 32 + lh * 16;
            #pragma unroll
            for (int n = 0; n < 3; ++n) {
                int ad = (cobase[n] + cioff2) ^ xorv;
                bf16x8 bh = __builtin_bit_cast(bf16x8, *(const short8*)(wlds + ad));
                acc[0][n] = __builtin_amdgcn_mfma_f32_32x32x16_bf16(av0, bh, acc[0][n], 0, 0, 0);
                acc[1][n] = __builtin_amdgcn_mfma_f32_32x32x16_bf16(av1, bh, acc[1][n], 0, 0, 0);
            }
        }
        if (k < 26) {
            idx0 = nbr[row0 * 27 + k + 1];
            idx1 = nbr[row1 * 27 + k + 1];
        }
    }

    #pragma unroll
    for (int ms = 0; ms < 2; ++ms)
        #pragma unroll
        for (int n = 0; n < 3; ++n)
            #pragma unroll
            for (int r = 0; r < 16; ++r) {
                int rw = (r & 3) + 8 * (r >> 2) + 4 * lh;
                hout[(long)(blockM + wv * 64 + ms * 32 + rw) * 96 + n * 32 + l31] = acc[ms][n][r];
            }

    float sv[3], qv[3], mv[3];
    #pragma unroll
    for (int n = 0; n < 3; ++n) { sv[n] = 0.f; qv[n] = 0.f; mv[n] = -INFINITY; }
    #pragma unroll
    for (int ms = 0; ms < 2; ++ms)
        #pragma unroll
        for (int n = 0; n < 3; ++n)
            #pragma unroll
            for (int r = 0; r < 16; ++r) {
                float v = acc[ms][n][r];
                sv[n] += v; qv[n] = fmaf(v, v, qv[n]); mv[n] = fmaxf(mv[n], v);
            }
    #pragma unroll
    for (int n = 0; n < 3; ++n) {
        sv[n] += __shfl_xor(sv[n], 32);
        qv[n] += __shfl_xor(qv[n], 32);
        mv[n] = fmaxf(mv[n], __shfl_xor(mv[n], 32));
    }
    if (lh == 0) {
        #pragma unroll
        for (int n = 0; n < 3; ++n) {
            red[wv][n][l31][0] = sv[n];
            red[wv][n][l31][1] = qv[n];
            red[wv][n][l31][2] = mv[n];
        }
    }
    __syncthreads();
    if (tid < 96) {
        int n = tid >> 5, c = tid & 31;
        float S = 0.f, Q = 0.f, M = -INFINITY;
        #pragma unroll
        for (int w = 0; w < 4; ++w) {
            S += red[w][n][c][0];
            Q += red[w][n][c][1];
            M = fmaxf(M, red[w][n][c][2]);
        }
        float* op = partials + (long)blockIdx.x * 288;
        op[tid] = S; op[96 + tid] = Q; op[192 + tid] = M;
    }
}

// ---------------------------------------------------------------------------
// Kernel reduce1: collapse 1024 partial rows -> 32 (16 per scene, 32 rows
// each). cols 0..191 sum, 192..287 max.
// ---------------------------------------------------------------------------
__global__ __launch_bounds__(384) void reduce1_kernel(
    const float* __restrict__ partials, float* __restrict__ out1)
{
    const int t = threadIdx.x;
    if (t >= 288) return;
    const int scene = blockIdx.x >> 4;
    const int slot  = blockIdx.x & 15;
    const float* pp = partials + ((long)scene * 512 + (long)slot * 32) * 288;
    float v = (t >= 192) ? -INFINITY : 0.f;
    for (int i = 0; i < 32; ++i) {
        float u = pp[i * 288 + t];
        v = (t >= 192) ? fmaxf(v, u) : (v + u);
    }
    out1[(long)blockIdx.x * 288 + t] = v;
}

// ---------------------------------------------------------------------------
// Kernel attn: reduce partials (4-way chunked, 384 thr) -> scene stats;
// attention MLP + softmax; analytic BN stats. Single block.
// ---------------------------------------------------------------------------
__global__ __launch_bounds__(384) void attn_kernel(
    const float* __restrict__ partials, int nper,
    const float* __restrict__ w1, const float* __restrict__ bias1,
    const float* __restrict__ w2, const float* __restrict__ bias2,
    float* __restrict__ smal)
{
    __shared__ float rS[2][4][96], rQ[2][4][96], rM[2][4][96];
    __shared__ float Sb[2][96], Qb[2][96];
    __shared__ float vecs[4][96];
    __shared__ float hid[4][48];
    __shared__ float logit[2][96];
    __shared__ float attn[2][96];
    __shared__ float red2[2][2];
    const int t = threadIdx.x;
    const int c = t % 96, j = t / 96;
    const int chunk = nper / 4;

    for (int b = 0; b < 2; ++b) {
        float s = 0.f, q = 0.f, m = -INFINITY;
        const float* pp = partials + (long)b * nper * 288 + (long)j * chunk * 288;
        for (int i = 0; i < chunk; ++i) {
            s += pp[i * 288 + c];
            q += pp[i * 288 + 96 + c];
            m = fmaxf(m, pp[i * 288 + 192 + c]);
        }
        rS[b][j][c] = s; rQ[b][j][c] = q; rM[b][j][c] = m;
    }
    __syncthreads();

    if (t < 96) {
        for (int b = 0; b < 2; ++b) {
            float s = 0.f, q = 0.f, m = -INFINITY;
            #pragma unroll
            for (int jj = 0; jj < 4; ++jj) {
                s += rS[b][jj][t];
                q += rQ[b][jj][t];
                m = fmaxf(m, rM[b][jj][t]);
            }
            Sb[b][t] = s;
            Qb[b][t] = q;
            vecs[2 * b][t]     = s * (1.0f / (float)NPB_);
            vecs[2 * b + 1][t] = m;
        }
    }
    __syncthreads();

    for (int v = 0; v < 4; ++v) {
        if (t < 48) {
            float a = bias1[t];
            for (int cc = 0; cc < 96; ++cc) a = fmaf(vecs[v][cc], w1[cc * 48 + t], a);
            hid[v][t] = fmaxf(a, 0.f);
        }
    }
    __syncthreads();

    if (t < 96) {
        for (int b = 0; b < 2; ++b) {
            float om = bias2[t], ox = bias2[t];
            for (int jj = 0; jj < 48; ++jj) {
                om = fmaf(hid[2 * b][jj],     w2[jj * 96 + t], om);
                ox = fmaf(hid[2 * b + 1][jj], w2[jj * 96 + t], ox);
            }
            logit[b][t] = fmaxf(om, 0.f) + fmaxf(ox, 0.f);
        }
    }
    __syncthreads();

    if (t < 2) {
        float mx = -INFINITY;
        for (int cc = 0; cc < 96; ++cc) mx = fmaxf(mx, logit[t][cc]);
        float s = 0.f;
        for (int cc = 0; cc < 96; ++cc) s += __expf(logit[t][cc] - mx);
        red2[t][0] = mx;
        red2[t][1] = s;
    }
    __syncthreads();
    if (t < 96) {
        for (int b = 0; b < 2; ++b)
            attn[b][t] = __expf(logit[b][t] - red2[b][0]) / red2[b][1];
    }
    __syncthreads();

    if (t < 96) {
        float a0 = attn[0][t], a1 = attn[1][t];
        const float invN = 1.0f / (float)NPTS;
        float mu = (a0 * Sb[0][t] + a1 * Sb[1][t]) * invN;
        float e2 = (a0 * a0 * Qb[0][t] + a1 * a1 * Qb[1][t]) * invN;
        float var = e2 - mu * mu;
        smal[t]       = a0;
        smal[96 + t]  = a1;
        smal[192 + t] = mu;
        smal[288 + t] = rsqrtf(var + EPS_);
    }
}

// ---------------------------------------------------------------------------
// Kernel finalize (in place on d_out which holds h):
// out = relu( relu(gamma*(h*attn - mu)*invstd + beta) + x )
// ---------------------------------------------------------------------------
__global__ __launch_bounds__(256) void final_kernel(
    const float* __restrict__ x, const float* __restrict__ smal,
    const float* __restrict__ gamma, const float* __restrict__ beta,
    float* __restrict__ out)
{
    const int nq = NPTS * 24;
    const int sceneq = NPB_ * 24;
    for (int i = blockIdx.x * 256 + threadIdx.x; i < nq; i += gridDim.x * 256) {
        const int b = (i >= sceneq) ? 1 : 0;
        const int q = i % 24;
        float4 h4 = ((const float4*)out)[i];
        float4 x4 = ((const float4*)x)[i];
        float4 a4  = ((const float4*)(smal + b * 96))[q];
        float4 mu4 = ((const float4*)(smal + 192))[q];
        float4 is4 = ((const float4*)(smal + 288))[q];
        float4 g4  = ((const float4*)gamma)[q];
        float4 be4 = ((const float4*)beta)[q];
        float4 r;
        r.x = fmaxf(fmaxf(fmaf((h4.x * a4.x - mu4.x) * is4.x, g4.x, be4.x), 0.f) + x4.x, 0.f);
        r.y = fmaxf(fmaxf(fmaf((h4.y * a4.y - mu4.y) * is4.y, g4.y, be4.y), 0.f) + x4.y, 0.f);
        r.z = fmaxf(fmaxf(fmaf((h4.z * a4.z - mu4.z) * is4.z, g4.z, be4.z), 0.f) + x4.z, 0.f);
        r.w = fmaxf(fmaxf(fmaf((h4.w * a4.w - mu4.w) * is4.w, g4.w, be4.w), 0.f) + x4.w, 0.f);
        ((float4*)out)[i] = r;
    }
}

// ---------------------------------------------------------------------------
extern "C" void kernel_launch(void* const* d_in, const int* in_sizes, int n_in,
                              void* d_out, int out_size, void* d_ws, size_t ws_size,
                              hipStream_t stream)
{
    const float* x     = (const float*)d_in[0];
    const int*   nbr   = (const int*)  d_in[1];
    const float* W     = (const float*)d_in[2];
    const float* w1    = (const float*)d_in[3];
    const float* b1    = (const float*)d_in[4];
    const float* w2    = (const float*)d_in[5];
    const float* b2    = (const float*)d_in[6];
    const float* gamma = (const float*)d_in[7];
    const float* beta  = (const float*)d_in[8];
    float* out = (float*)d_out;

    const size_t WT_BYTES   = 27UL * WTAP;                   // 497664
    const size_t XS_BYTES   = (size_t)(NPTS + 1) * 96 * 2;   // ~50.3 MB (+zero row)
    const size_t PART_BYTES = 1024UL * 288 * 4;              // 1179648
    const size_t OUT1_BYTES = 32UL * 288 * 4;                // 36864

    char* wt = (char*)d_ws;
    wprep_kernel<<<972, 256, 0, stream>>>(W, wt);

    if (ws_size >= WT_BYTES + XS_BYTES + PART_BYTES + OUT1_BYTES + 2048) {
        unsigned short* xs = (unsigned short*)(wt + WT_BYTES);
        float* partials = (float*)(wt + WT_BYTES + XS_BYTES);
        float* out1     = partials + 1024 * 288;
        float* smal     = out1 + 32 * 288;
        xprep_kernel  <<<2048, 256, 0, stream>>>(x, xs);
        conv_mfma     <<<1024, 512, 0, stream>>>(xs, nbr, wt, out, partials);
        reduce1_kernel<<<32, 384, 0, stream>>>(partials, out1);
        attn_kernel   <<<1, 384, 0, stream>>>(out1, 16, w1, b1, w2, b2, smal);
        final_kernel  <<<1024, 256, 0, stream>>>(x, smal, gamma, beta, out);
    } else {
        float* partials = (float*)(wt + WT_BYTES);
        float* smal     = partials + 1024 * 288;
        conv_mfma_cvt<<<1024, 256, 0, stream>>>(x, nbr, wt, out, partials);
        attn_kernel  <<<1, 384, 0, stream>>>(partials, 512, w1, b1, w2, b2, smal);
        final_kernel <<<1024, 256, 0, stream>>>(x, smal, gamma, beta, out);
    }
}